// Round 18
// baseline (394.315 us; speedup 1.0000x reference)
//
#include <hip/hip_runtime.h>
#include <hip/hip_bf16.h>
#include <math.h>

typedef __bf16 bf16x8 __attribute__((ext_vector_type(8)));
typedef float  f32x4  __attribute__((ext_vector_type(4)));

#define MFMA16 __builtin_amdgcn_mfma_f32_16x16x32_bf16

__device__ __forceinline__ float silu_f(float v) {
    return v * __builtin_amdgcn_rcpf(1.0f + __expf(-v));
}

// LDS weight layout: Wt[j][k], bf16, 16B-chunk XOR swizzle:
// phys = j*K + (((k>>3) ^ (j&7))<<3) + (k&7)  -> ds_read_b128, 2-way max.

// ---- detector: is edge_index stored as int64 (odd words all zero)? ---------
__global__ void k_detect(const int* __restrict__ ei, int* __restrict__ flag) {
    __shared__ int red[256];
    int v = 0;
#pragma unroll
    for (int j = 0; j < 4; ++j) v |= ei[2 * (threadIdx.x * 4 + j) + 1];
    red[threadIdx.x] = v;
    __syncthreads();
    for (int s = 128; s > 0; s >>= 1) {
        if (threadIdx.x < s) red[threadIdx.x] |= red[threadIdx.x + s];
        __syncthreads();
    }
    if (threadIdx.x == 0) *flag = (red[0] == 0) ? 1 : 0;
}

// ---- CSR build --------------------------------------------------------------
__global__ __launch_bounds__(256) void k_hist(
    const int* __restrict__ ei, const int* __restrict__ flag,
    int* __restrict__ counts, int E)
{
    int e = blockIdx.x * 256 + threadIdx.x;
    if (e >= E) return;
    const int is64 = *flag;
    int r = is64 ? ei[2 * E + 2 * e] : ei[E + e];
    atomicAdd(&counts[r], 1);
}

__global__ __launch_bounds__(256) void k_scan1(
    const int* __restrict__ counts, int* __restrict__ offsets,
    int* __restrict__ partials, int N)
{
    __shared__ int pairv[256];
    __shared__ int buf[256];
    const int t = threadIdx.x;
    const int base = blockIdx.x * 512;
    int a = (base + 2 * t     < N) ? counts[base + 2 * t]     : 0;
    int b = (base + 2 * t + 1 < N) ? counts[base + 2 * t + 1] : 0;
    pairv[t] = a + b;
    buf[t]   = a + b;
    __syncthreads();
    for (int d = 1; d < 256; d <<= 1) {
        int v = buf[t];
        int w = (t >= d) ? buf[t - d] : 0;
        __syncthreads();
        buf[t] = v + w;
        __syncthreads();
    }
    int excl = buf[t] - pairv[t];
    if (base + 2 * t     < N) offsets[base + 2 * t]     = excl;
    if (base + 2 * t + 1 < N) offsets[base + 2 * t + 1] = excl + a;
    if (t == 255) partials[blockIdx.x] = buf[255];
}

__global__ void k_scan2(int* __restrict__ partials, int nblk) {
    __shared__ int buf[256];
    const int t = threadIdx.x;
    int v0 = (t < nblk) ? partials[t] : 0;
    buf[t] = v0;
    __syncthreads();
    for (int d = 1; d < 256; d <<= 1) {
        int v = buf[t];
        int w = (t >= d) ? buf[t - d] : 0;
        __syncthreads();
        buf[t] = v + w;
        __syncthreads();
    }
    if (t < nblk) partials[t] = buf[t] - v0;   // exclusive
}

__global__ __launch_bounds__(256) void k_scan3(
    int* __restrict__ offsets, const int* __restrict__ partials,
    int* __restrict__ cursor, int N)
{
    int i = blockIdx.x * 256 + threadIdx.x;
    if (i >= N) return;
    int v = offsets[i] + partials[i >> 9];
    offsets[i] = v;
    cursor[i]  = v;
}

// scatter + per-edge distance precompute (kills pos-gather chains downstream)
__global__ __launch_bounds__(256) void k_scatter(
    const int* __restrict__ ei, const int* __restrict__ flag,
    const float* __restrict__ pos, int* __restrict__ cursor,
    int* __restrict__ csr_s, int* __restrict__ csr_r,
    float* __restrict__ dist, int E)
{
    int e = blockIdx.x * 256 + threadIdx.x;
    if (e >= E) return;
    const int is64 = *flag;
    int s, r;
    if (is64) { s = ei[2 * e]; r = ei[2 * E + 2 * e]; }
    else      { s = ei[e];     r = ei[E + e];         }
    float dx = pos[3 * s]     - pos[3 * r];
    float dy = pos[3 * s + 1] - pos[3 * r + 1];
    float dz = pos[3 * s + 2] - pos[3 * r + 2];
    float d  = sqrtf(dx * dx + dy * dy + dz * dz);
    int slot = atomicAdd(&cursor[r], 1);
    csr_s[slot] = s;
    csr_r[slot] = r;
    dist[slot]  = d;
}

// ---- phase 1: AB[n][0:128]=bf16(x@W1a + b1), AB[n][128:256]=bf16(x@W1b) ----
__global__ __launch_bounds__(256) void k_node1(
    const float* __restrict__ x, const float* __restrict__ W1,
    const float* __restrict__ b1, __bf16* __restrict__ AB, int N, int ngroups)
{
    __shared__ __bf16 wt[256 * 128];
    for (int idx = threadIdx.x; idx < 256 * 128; idx += 256) {
        int j = idx & 255, k = idx >> 8;
        float w = (j < 128) ? W1[(k << 7) + j] : W1[((k + 128) << 7) + (j - 128)];
        wt[(j << 7) + ((((k >> 3) ^ (j & 7))) << 3) + (k & 7)] = (__bf16)w;
    }
    __syncthreads();

    const int lane = threadIdx.x & 63;
    const int row  = lane & 15;
    const int kq   = lane >> 4;

    for (int g = blockIdx.x; g < ngroups; g += gridDim.x) {
        const int row0 = g * 64 + (threadIdx.x >> 6) * 16;
        int m = row0 + row; if (m >= N) m = N - 1;
        const float* xr = x + (size_t)m * 128;

        bf16x8 afr[4];
#pragma unroll
        for (int c = 0; c < 4; ++c) {
            const int k0 = c * 32 + kq * 8;
            float4 a0 = *(const float4*)(xr + k0);
            float4 a1 = *(const float4*)(xr + k0 + 4);
            bf16x8 af;
            af[0]=(__bf16)a0.x; af[1]=(__bf16)a0.y; af[2]=(__bf16)a0.z; af[3]=(__bf16)a0.w;
            af[4]=(__bf16)a1.x; af[5]=(__bf16)a1.y; af[6]=(__bf16)a1.z; af[7]=(__bf16)a1.w;
            afr[c] = af;
        }

        f32x4 acc[16] = {};
#pragma unroll
        for (int t = 0; t < 16; ++t) {
            const int j  = t * 16 + row;
            const int jb = j & 7;
            const __bf16* base = wt + (j << 7);
#pragma unroll
            for (int c = 0; c < 4; ++c) {
                const int kb = c * 4 + kq;
                bf16x8 b = *(const bf16x8*)(base + ((kb ^ jb) << 3));
                acc[t] = MFMA16(afr[c], b, acc[t], 0, 0, 0);
            }
        }

#pragma unroll
        for (int t = 0; t < 16; ++t) {
            const int col = t * 16 + row;
            const float bb = (col < 128) ? b1[col] : 0.0f;
#pragma unroll
            for (int q = 0; q < 4; ++q) {
                const int gr = row0 + kq * 4 + q;
                if (gr < N) AB[(size_t)gr * 256 + col] = (__bf16)(acc[t][q] + bb);
            }
        }
    }
}

// ---- FUSED edge v8: wave-per-receiver, first layer ONCE, afr in LDS stash --
// Half-pass 0 consumes each af chunk from registers (c-innermost) while also
// ds_writing it to the wave's stash; half-pass 1 re-reads chunks from LDS.
// Stash is lane-private (own write, own read -> no sync) and XOR-swizzled
// (el ^= (row&7)<<3) to avoid the 16-way row*256B bank conflict.
__global__ __launch_bounds__(256) void k_edge_f8(
    const __bf16* __restrict__ AB, const int* __restrict__ csr_s,
    const float* __restrict__ dist, const int* __restrict__ offs,
    const int* __restrict__ counts, const float* __restrict__ W2,
    const float* __restrict__ b2, const float* __restrict__ w3,
    float* __restrict__ aggr, int N)
{
    __shared__ __bf16 wt[128 * 128];        // 32 KB W2^T swizzled
    __shared__ float  w3s[128];
    __shared__ float  b2s[128];
    __shared__ __bf16 bsl[4][128];          // per-wave B-row slot
    __shared__ __bf16 stash[4][16 * 128];   // 16 KB: per-wave h-tile stash
    for (int idx = threadIdx.x; idx < 128 * 128; idx += 256) {
        int j = idx & 127, k = idx >> 7;
        wt[(j << 7) + ((((k >> 3) ^ (j & 7))) << 3) + (k & 7)] = (__bf16)W2[(k << 7) + j];
    }
    for (int i = threadIdx.x; i < 128; i += 256) { w3s[i] = w3[i]; b2s[i] = b2[i]; }
    __syncthreads();

    const int lane = threadIdx.x & 63;
    const int row  = lane & 15;
    const int kq   = lane >> 4;
    const int wid  = threadIdx.x >> 6;
    const int wstep = gridDim.x * 4;
    __bf16* st = &stash[wid][row * 128];
    const int swz = (row & 7) << 3;          // element-unit XOR swizzle

    for (int r = blockIdx.x * 4 + wid; r < N; r += wstep) {
        const int off = offs[r];
        const int deg = counts[r];

        if (lane < 16)
            *(bf16x8*)(&bsl[wid][lane * 8]) =
                *(const bf16x8*)(AB + (size_t)r * 256 + 128 + lane * 8);

        float colacc[8] = {0, 0, 0, 0, 0, 0, 0, 0};

        const int ntile = (deg + 15) >> 4;
        for (int tile = 0; tile < ntile; ++tile) {
            const int el  = tile * 16 + row;
            const int idx = off + ((el < deg) ? el : (deg - 1));
            const int s   = csr_s[idx];
            const float d = dist[idx];

            // ---- half-pass 0: first layer (once) + cols 0..63, stash af ---
            f32x4 acc[4] = {};
#pragma unroll
            for (int c = 0; c < 4; ++c) {
                const int k0 = c * 32 + kq * 8;
                bf16x8 a  = *(const bf16x8*)(AB + (size_t)s * 256 + k0);
                bf16x8 bb = *(const bf16x8*)(&bsl[wid][k0]);
                float4 w0 = *(const float4*)(w3s + k0);
                float4 w1 = *(const float4*)(w3s + k0 + 4);
                bf16x8 af;
                af[0] = (__bf16)silu_f((float)a[0] + (float)bb[0] + d * w0.x);
                af[1] = (__bf16)silu_f((float)a[1] + (float)bb[1] + d * w0.y);
                af[2] = (__bf16)silu_f((float)a[2] + (float)bb[2] + d * w0.z);
                af[3] = (__bf16)silu_f((float)a[3] + (float)bb[3] + d * w0.w);
                af[4] = (__bf16)silu_f((float)a[4] + (float)bb[4] + d * w1.x);
                af[5] = (__bf16)silu_f((float)a[5] + (float)bb[5] + d * w1.y);
                af[6] = (__bf16)silu_f((float)a[6] + (float)bb[6] + d * w1.z);
                af[7] = (__bf16)silu_f((float)a[7] + (float)bb[7] + d * w1.w);
                *(bf16x8*)(st + (k0 ^ swz)) = af;        // stash for pass 1
                const int kb = c * 4 + kq;
#pragma unroll
                for (int t4 = 0; t4 < 4; ++t4) {
                    const int j  = t4 * 16 + row;
                    const int jb = j & 7;
                    bf16x8 b = *(const bf16x8*)(wt + (j << 7) + ((kb ^ jb) << 3));
                    acc[t4] = MFMA16(af, b, acc[t4], 0, 0, 0);
                }
            }
#pragma unroll
            for (int t4 = 0; t4 < 4; ++t4) {
                const float bb = b2s[t4 * 16 + row];
#pragma unroll
                for (int q = 0; q < 4; ++q) {
                    const int er = tile * 16 + kq * 4 + q;
                    if (er < deg) colacc[t4] += silu_f(acc[t4][q] + bb);
                }
            }

            // ---- half-pass 1: cols 64..127, af re-read from stash ---------
#pragma unroll
            for (int t4 = 0; t4 < 4; ++t4) acc[t4] = (f32x4){};
#pragma unroll
            for (int c = 0; c < 4; ++c) {
                const int k0 = c * 32 + kq * 8;
                bf16x8 af = *(const bf16x8*)(st + (k0 ^ swz));
                const int kb = c * 4 + kq;
#pragma unroll
                for (int t4 = 0; t4 < 4; ++t4) {
                    const int j  = (4 + t4) * 16 + row;
                    const int jb = j & 7;
                    bf16x8 b = *(const bf16x8*)(wt + (j << 7) + ((kb ^ jb) << 3));
                    acc[t4] = MFMA16(af, b, acc[t4], 0, 0, 0);
                }
            }
#pragma unroll
            for (int t4 = 0; t4 < 4; ++t4) {
                const float bb = b2s[(4 + t4) * 16 + row];
#pragma unroll
                for (int q = 0; q < 4; ++q) {
                    const int er = tile * 16 + kq * 4 + q;
                    if (er < deg) colacc[4 + t4] += silu_f(acc[t4][q] + bb);
                }
            }
        }

#pragma unroll
        for (int t = 0; t < 8; ++t) {
            float v = colacc[t];
            v += __shfl_xor(v, 16, 64);
            v += __shfl_xor(v, 32, 64);
            colacc[t] = v;
        }
        if (kq == 0) {
#pragma unroll
            for (int t = 0; t < 8; ++t)
                aggr[(size_t)r * 128 + t * 16 + row] = colacc[t];
        }
    }
}

// ---- FUSED edge v4 (fallback, 128 VGPR measured): column-split -------------
__global__ __launch_bounds__(256) void k_edge_f4(
    const __bf16* __restrict__ AB, const int* __restrict__ csr_s,
    const float* __restrict__ dist, const int* __restrict__ offs,
    const int* __restrict__ counts, const float* __restrict__ W2,
    const float* __restrict__ b2, const float* __restrict__ w3,
    float* __restrict__ aggr, int N)
{
    __shared__ __bf16 wt[128 * 128];
    __shared__ float  w3s[128];
    __shared__ float  b2s[128];
    __shared__ __bf16 bsl[4][128];
    for (int idx = threadIdx.x; idx < 128 * 128; idx += 256) {
        int j = idx & 127, k = idx >> 7;
        wt[(j << 7) + ((((k >> 3) ^ (j & 7))) << 3) + (k & 7)] = (__bf16)W2[(k << 7) + j];
    }
    for (int i = threadIdx.x; i < 128; i += 256) { w3s[i] = w3[i]; b2s[i] = b2[i]; }
    __syncthreads();

    const int lane = threadIdx.x & 63;
    const int row  = lane & 15;
    const int kq   = lane >> 4;
    const int wid  = threadIdx.x >> 6;
    const int wstep = gridDim.x * 4;
    const int nslot = 2 * N;

    for (int v = blockIdx.x * 4 + wid; v < nslot; v += wstep) {
        const int r  = v >> 1;
        const int hf = v & 1;
        const int off = offs[r];
        const int deg = counts[r];

        if (lane < 16)
            *(bf16x8*)(&bsl[wid][lane * 8]) =
                *(const bf16x8*)(AB + (size_t)r * 256 + 128 + lane * 8);

        float colacc[4] = {0, 0, 0, 0};

        const int ntile = (deg + 15) >> 4;
        for (int tile = 0; tile < ntile; ++tile) {
            const int el  = tile * 16 + row;
            const int idx = off + ((el < deg) ? el : (deg - 1));
            const int s   = csr_s[idx];
            const float d = dist[idx];

            f32x4 acc[4] = {};
#pragma unroll
            for (int c = 0; c < 4; ++c) {
                const int k0 = c * 32 + kq * 8;
                bf16x8 a  = *(const bf16x8*)(AB + (size_t)s * 256 + k0);
                bf16x8 bb = *(const bf16x8*)(&bsl[wid][k0]);
                float4 w0 = *(const float4*)(w3s + k0);
                float4 w1 = *(const float4*)(w3s + k0 + 4);
                bf16x8 af;
                af[0] = (__bf16)silu_f((float)a[0] + (float)bb[0] + d * w0.x);
                af[1] = (__bf16)silu_f((float)a[1] + (float)bb[1] + d * w0.y);
                af[2] = (__bf16)silu_f((float)a[2] + (float)bb[2] + d * w0.z);
                af[3] = (__bf16)silu_f((float)a[3] + (float)bb[3] + d * w0.w);
                af[4] = (__bf16)silu_f((float)a[4] + (float)bb[4] + d * w1.x);
                af[5] = (__bf16)silu_f((float)a[5] + (float)bb[5] + d * w1.y);
                af[6] = (__bf16)silu_f((float)a[6] + (float)bb[6] + d * w1.z);
                af[7] = (__bf16)silu_f((float)a[7] + (float)bb[7] + d * w1.w);
                const int kb = c * 4 + kq;
#pragma unroll
                for (int t4 = 0; t4 < 4; ++t4) {
                    const int j  = (hf * 4 + t4) * 16 + row;
                    const int jb = j & 7;
                    bf16x8 b = *(const bf16x8*)(wt + (j << 7) + ((kb ^ jb) << 3));
                    acc[t4] = MFMA16(af, b, acc[t4], 0, 0, 0);
                }
            }

#pragma unroll
            for (int t4 = 0; t4 < 4; ++t4) {
                const float bb = b2s[(hf * 4 + t4) * 16 + row];
#pragma unroll
                for (int q = 0; q < 4; ++q) {
                    const int er = tile * 16 + kq * 4 + q;
                    if (er < deg) colacc[t4] += silu_f(acc[t4][q] + bb);
                }
            }
        }

#pragma unroll
        for (int t4 = 0; t4 < 4; ++t4) {
            float vv = colacc[t4];
            vv += __shfl_xor(vv, 16, 64);
            vv += __shfl_xor(vv, 32, 64);
            colacc[t4] = vv;
        }
        if (kq == 0) {
#pragma unroll
            for (int t4 = 0; t4 < 4; ++t4)
                aggr[(size_t)r * 128 + (hf * 4 + t4) * 16 + row] = colacc[t4];
        }
    }
}

// -------- phase 3: u = silu(x@U1a + aggr@U1b + c1), bf16, IN PLACE over aggr
__global__ __launch_bounds__(256) void k_node2(
    const float* __restrict__ x, const float* __restrict__ aggr,
    const float* __restrict__ U1, const float* __restrict__ c1,
    __bf16* __restrict__ u, int N, int ngroups)
{
    __shared__ __bf16 wt[128 * 256];
    for (int idx = threadIdx.x; idx < 128 * 256; idx += 256) {
        int j = idx & 127, k = idx >> 7;
        wt[(j << 8) + ((((k >> 3) ^ (j & 7))) << 3) + (k & 7)] = (__bf16)U1[(k << 7) + j];
    }
    __syncthreads();

    const int lane = threadIdx.x & 63;
    const int row  = lane & 15;
    const int kq   = lane >> 4;

    for (int g = blockIdx.x; g < ngroups; g += gridDim.x) {
        const int row0 = g * 64 + (threadIdx.x >> 6) * 16;
        int m = row0 + row; if (m >= N) m = N - 1;

        bf16x8 afr[8];
#pragma unroll
        for (int c = 0; c < 8; ++c) {
            const int k0 = (c & 3) * 32 + kq * 8;
            const float* src = (c < 4) ? (x + (size_t)m * 128 + k0)
                                       : (aggr + (size_t)m * 128 + k0);
            float4 a0 = *(const float4*)(src);
            float4 a1 = *(const float4*)(src + 4);
            bf16x8 af;
            af[0]=(__bf16)a0.x; af[1]=(__bf16)a0.y; af[2]=(__bf16)a0.z; af[3]=(__bf16)a0.w;
            af[4]=(__bf16)a1.x; af[5]=(__bf16)a1.y; af[6]=(__bf16)a1.z; af[7]=(__bf16)a1.w;
            afr[c] = af;
        }

        f32x4 acc[8] = {};
#pragma unroll
        for (int t = 0; t < 8; ++t) {
            const int j  = t * 16 + row;
            const int jb = j & 7;
            const __bf16* base = wt + (j << 8);
#pragma unroll
            for (int c = 0; c < 8; ++c) {
                const int kb = c * 4 + kq;
                bf16x8 b = *(const bf16x8*)(base + ((kb ^ jb) << 3));
                acc[t] = MFMA16(afr[c], b, acc[t], 0, 0, 0);
            }
        }

#pragma unroll
        for (int t = 0; t < 8; ++t) {
            const int col = t * 16 + row;
            const float cc = c1[col];
#pragma unroll
            for (int q = 0; q < 4; ++q) {
                const int gr = row0 + kq * 4 + q;
                if (gr < N) u[(size_t)gr * 256 + col] = (__bf16)silu_f(acc[t][q] + cc);
            }
        }
    }
}

// ---------------- phase 4: out = u@U2 + c2 (overwrites AB in d_out) ---------
__global__ __launch_bounds__(256) void k_node3(
    const __bf16* __restrict__ u, const float* __restrict__ U2,
    const float* __restrict__ c2, float* __restrict__ out, int N, int ngroups)
{
    __shared__ __bf16 wt[128 * 128];
    for (int idx = threadIdx.x; idx < 128 * 128; idx += 256) {
        int j = idx & 127, k = idx >> 7;
        wt[(j << 7) + ((((k >> 3) ^ (j & 7))) << 3) + (k & 7)] = (__bf16)U2[(k << 7) + j];
    }
    __syncthreads();

    const int lane = threadIdx.x & 63;
    const int row  = lane & 15;
    const int kq   = lane >> 4;

    for (int g = blockIdx.x; g < ngroups; g += gridDim.x) {
        const int row0 = g * 64 + (threadIdx.x >> 6) * 16;
        int m = row0 + row; if (m >= N) m = N - 1;

        bf16x8 afr[4];
#pragma unroll
        for (int c = 0; c < 4; ++c) {
            const int k0 = c * 32 + kq * 8;
            afr[c] = *(const bf16x8*)(u + (size_t)m * 256 + k0);
        }

        f32x4 acc[8] = {};
#pragma unroll
        for (int t = 0; t < 8; ++t) {
            const int j  = t * 16 + row;
            const int jb = j & 7;
            const __bf16* base = wt + (j << 7);
#pragma unroll
            for (int c = 0; c < 4; ++c) {
                const int kb = c * 4 + kq;
                bf16x8 b = *(const bf16x8*)(base + ((kb ^ jb) << 3));
                acc[t] = MFMA16(afr[c], b, acc[t], 0, 0, 0);
            }
        }

#pragma unroll
        for (int t = 0; t < 8; ++t) {
            const int col = t * 16 + row;
            const float cc = c2[col];
#pragma unroll
            for (int q = 0; q < 4; ++q) {
                const int gr = row0 + kq * 4 + q;
                if (gr < N) out[(size_t)gr * 128 + col] = acc[t][q] + cc;
            }
        }
    }
}

extern "C" void kernel_launch(void* const* d_in, const int* in_sizes, int n_in,
                              void* d_out, int out_size, void* d_ws, size_t ws_size,
                              hipStream_t stream) {
    (void)n_in; (void)out_size;
    const float* x   = (const float*)d_in[0];
    const float* pos = (const float*)d_in[1];
    const int*   ei  = (const int*)d_in[2];
    const float* W1  = (const float*)d_in[3];
    const float* b1  = (const float*)d_in[4];
    const float* W2  = (const float*)d_in[5];
    const float* b2  = (const float*)d_in[6];
    const float* U1  = (const float*)d_in[7];
    const float* c1  = (const float*)d_in[8];
    const float* U2  = (const float*)d_in[9];
    const float* c2  = (const float*)d_in[10];

    const int N = in_sizes[0] / 128;
    const int E = in_sizes[2] / 2;

    // ---- workspace layout (16B-aligned slabs) ----
    const size_t aggr_b = (size_t)N * 128 * sizeof(float);
    const size_t Ni_b   = (((size_t)N * 4) + 15) & ~(size_t)15;
    const size_t E_b    = (((size_t)E * 4) + 15) & ~(size_t)15;
    size_t off = 0;
    char* base = (char*)d_ws;
    float* aggr   = (float*)(base + off); off += aggr_b;
    int*   flag   = (int*)  (base + off); off += 16;
    int*   counts = (int*)  (base + off); off += Ni_b;
    int*   offs   = (int*)  (base + off); off += Ni_b;
    int*   cursor = (int*)  (base + off); off += Ni_b;
    int*   parts  = (int*)  (base + off); off += 256 * 4;
    int*   csr_s  = (int*)  (base + off); off += E_b;
    int*   csr_r  = (int*)  (base + off); off += E_b;
    float* dist   = (float*)(base + off); off += E_b;
    const size_t need_csr = off;

    __bf16* u  = (__bf16*)d_ws;        // row stride 256 elem, aliases aggr
    __bf16* AB = (__bf16*)d_out;       // N*256 bf16 == out_nbytes

    const int nblk_scan = (N + 511) / 512;
    const bool csr_ok = (ws_size >= need_csr) && (nblk_scan <= 256);
    if (ws_size < aggr_b + 16 || !csr_ok) return;

    // calibrated selection (r16 ground truth: 128 regs = 4 waves/SIMD, good)
    hipFuncAttributes fa8{};
    const bool use_f8 =
        (hipFuncGetAttributes(&fa8, (const void*)k_edge_f8) == hipSuccess) &&
        (fa8.numRegs <= 128);

    const int ng_nodes = (N + 63) / 64;
    const int grid_n   = ng_nodes < 512 ? ng_nodes : 512;
    const int grid_E   = (E + 255) / 256;
    const int grid_Nt  = (N + 255) / 256;
    const int grid_f8  = ((N + 3) / 4) < 2048 ? ((N + 3) / 4) : 2048;
    const int nslot    = 2 * N;
    const int grid_f4  = ((nslot + 3) / 4) < 2048 ? ((nslot + 3) / 4) : 2048;

    k_detect<<<1, 256, 0, stream>>>(ei, flag);
    k_node1<<<grid_n, 256, 0, stream>>>(x, W1, b1, AB, N, ng_nodes);

    hipMemsetAsync(counts, 0, (size_t)N * 4, stream);
    k_hist   <<<grid_E, 256, 0, stream>>>(ei, flag, counts, E);
    k_scan1  <<<nblk_scan, 256, 0, stream>>>(counts, offs, parts, N);
    k_scan2  <<<1, 256, 0, stream>>>(parts, nblk_scan);
    k_scan3  <<<grid_Nt, 256, 0, stream>>>(offs, parts, cursor, N);
    k_scatter<<<grid_E, 256, 0, stream>>>(ei, flag, pos, cursor,
                                          csr_s, csr_r, dist, E);

    if (use_f8) {
        k_edge_f8<<<grid_f8, 256, 0, stream>>>(AB, csr_s, dist, offs, counts,
                                               W2, b2, W1 + 256 * 128, aggr, N);
    } else {
        k_edge_f4<<<grid_f4, 256, 0, stream>>>(AB, csr_s, dist, offs, counts,
                                               W2, b2, W1 + 256 * 128, aggr, N);
    }

    k_node2<<<grid_n, 256, 0, stream>>>(x, aggr, U1, c1, u, N, ng_nodes);
    k_node3<<<grid_n, 256, 0, stream>>>(u, U2, c2, (float*)d_out, N, ng_nodes);
}

// Round 19
// 362.649 us; speedup vs baseline: 1.0873x; 1.0873x over previous
//
#include <hip/hip_runtime.h>
#include <hip/hip_bf16.h>
#include <math.h>

typedef __bf16 bf16x8 __attribute__((ext_vector_type(8)));
typedef float  f32x4  __attribute__((ext_vector_type(4)));

#define MFMA16 __builtin_amdgcn_mfma_f32_16x16x32_bf16

__device__ __forceinline__ float silu_f(float v) {
    return v * __builtin_amdgcn_rcpf(1.0f + __expf(-v));
}

// LDS weight layout: Wt[j][k], bf16, 16B-chunk XOR swizzle:
// phys = j*K + (((k>>3) ^ (j&7))<<3) + (k&7)  -> ds_read_b128, 2-way max.

// ---- detector: is edge_index stored as int64 (odd words all zero)? ---------
__global__ void k_detect(const int* __restrict__ ei, int* __restrict__ flag) {
    __shared__ int red[256];
    int v = 0;
#pragma unroll
    for (int j = 0; j < 4; ++j) v |= ei[2 * (threadIdx.x * 4 + j) + 1];
    red[threadIdx.x] = v;
    __syncthreads();
    for (int s = 128; s > 0; s >>= 1) {
        if (threadIdx.x < s) red[threadIdx.x] |= red[threadIdx.x + s];
        __syncthreads();
    }
    if (threadIdx.x == 0) *flag = (red[0] == 0) ? 1 : 0;
}

// ---- CSR build --------------------------------------------------------------
__global__ __launch_bounds__(256) void k_hist(
    const int* __restrict__ ei, const int* __restrict__ flag,
    int* __restrict__ counts, int E)
{
    int e = blockIdx.x * 256 + threadIdx.x;
    if (e >= E) return;
    const int is64 = *flag;
    int r = is64 ? ei[2 * E + 2 * e] : ei[E + e];
    atomicAdd(&counts[r], 1);
}

__global__ __launch_bounds__(256) void k_scan1(
    const int* __restrict__ counts, int* __restrict__ offsets,
    int* __restrict__ partials, int N)
{
    __shared__ int pairv[256];
    __shared__ int buf[256];
    const int t = threadIdx.x;
    const int base = blockIdx.x * 512;
    int a = (base + 2 * t     < N) ? counts[base + 2 * t]     : 0;
    int b = (base + 2 * t + 1 < N) ? counts[base + 2 * t + 1] : 0;
    pairv[t] = a + b;
    buf[t]   = a + b;
    __syncthreads();
    for (int d = 1; d < 256; d <<= 1) {
        int v = buf[t];
        int w = (t >= d) ? buf[t - d] : 0;
        __syncthreads();
        buf[t] = v + w;
        __syncthreads();
    }
    int excl = buf[t] - pairv[t];
    if (base + 2 * t     < N) offsets[base + 2 * t]     = excl;
    if (base + 2 * t + 1 < N) offsets[base + 2 * t + 1] = excl + a;
    if (t == 255) partials[blockIdx.x] = buf[255];
}

__global__ void k_scan2(int* __restrict__ partials, int nblk) {
    __shared__ int buf[256];
    const int t = threadIdx.x;
    int v0 = (t < nblk) ? partials[t] : 0;
    buf[t] = v0;
    __syncthreads();
    for (int d = 1; d < 256; d <<= 1) {
        int v = buf[t];
        int w = (t >= d) ? buf[t - d] : 0;
        __syncthreads();
        buf[t] = v + w;
        __syncthreads();
    }
    if (t < nblk) partials[t] = buf[t] - v0;   // exclusive
}

__global__ __launch_bounds__(256) void k_scan3(
    int* __restrict__ offsets, const int* __restrict__ partials,
    int* __restrict__ cursor, int N)
{
    int i = blockIdx.x * 256 + threadIdx.x;
    if (i >= N) return;
    int v = offsets[i] + partials[i >> 9];
    offsets[i] = v;
    cursor[i]  = v;
}

// scatter + per-edge distance precompute (kills pos-gather chains downstream)
__global__ __launch_bounds__(256) void k_scatter(
    const int* __restrict__ ei, const int* __restrict__ flag,
    const float* __restrict__ pos, int* __restrict__ cursor,
    int* __restrict__ csr_s, int* __restrict__ csr_r,
    float* __restrict__ dist, int E)
{
    int e = blockIdx.x * 256 + threadIdx.x;
    if (e >= E) return;
    const int is64 = *flag;
    int s, r;
    if (is64) { s = ei[2 * e]; r = ei[2 * E + 2 * e]; }
    else      { s = ei[e];     r = ei[E + e];         }
    float dx = pos[3 * s]     - pos[3 * r];
    float dy = pos[3 * s + 1] - pos[3 * r + 1];
    float dz = pos[3 * s + 2] - pos[3 * r + 2];
    float d  = sqrtf(dx * dx + dy * dy + dz * dz);
    int slot = atomicAdd(&cursor[r], 1);
    csr_s[slot] = s;
    csr_r[slot] = r;
    dist[slot]  = d;
}

// ---- phase 1: AB[n][0:128]=bf16(x@W1a + b1), AB[n][128:256]=bf16(x@W1b) ----
__global__ __launch_bounds__(256) void k_node1(
    const float* __restrict__ x, const float* __restrict__ W1,
    const float* __restrict__ b1, __bf16* __restrict__ AB, int N, int ngroups)
{
    __shared__ __bf16 wt[256 * 128];
    for (int idx = threadIdx.x; idx < 256 * 128; idx += 256) {
        int j = idx & 255, k = idx >> 8;
        float w = (j < 128) ? W1[(k << 7) + j] : W1[((k + 128) << 7) + (j - 128)];
        wt[(j << 7) + ((((k >> 3) ^ (j & 7))) << 3) + (k & 7)] = (__bf16)w;
    }
    __syncthreads();

    const int lane = threadIdx.x & 63;
    const int row  = lane & 15;
    const int kq   = lane >> 4;

    for (int g = blockIdx.x; g < ngroups; g += gridDim.x) {
        const int row0 = g * 64 + (threadIdx.x >> 6) * 16;
        int m = row0 + row; if (m >= N) m = N - 1;
        const float* xr = x + (size_t)m * 128;

        bf16x8 afr[4];
#pragma unroll
        for (int c = 0; c < 4; ++c) {
            const int k0 = c * 32 + kq * 8;
            float4 a0 = *(const float4*)(xr + k0);
            float4 a1 = *(const float4*)(xr + k0 + 4);
            bf16x8 af;
            af[0]=(__bf16)a0.x; af[1]=(__bf16)a0.y; af[2]=(__bf16)a0.z; af[3]=(__bf16)a0.w;
            af[4]=(__bf16)a1.x; af[5]=(__bf16)a1.y; af[6]=(__bf16)a1.z; af[7]=(__bf16)a1.w;
            afr[c] = af;
        }

        f32x4 acc[16] = {};
#pragma unroll
        for (int t = 0; t < 16; ++t) {
            const int j  = t * 16 + row;
            const int jb = j & 7;
            const __bf16* base = wt + (j << 7);
#pragma unroll
            for (int c = 0; c < 4; ++c) {
                const int kb = c * 4 + kq;
                bf16x8 b = *(const bf16x8*)(base + ((kb ^ jb) << 3));
                acc[t] = MFMA16(afr[c], b, acc[t], 0, 0, 0);
            }
        }

#pragma unroll
        for (int t = 0; t < 16; ++t) {
            const int col = t * 16 + row;
            const float bb = (col < 128) ? b1[col] : 0.0f;
#pragma unroll
            for (int q = 0; q < 4; ++q) {
                const int gr = row0 + kq * 4 + q;
                if (gr < N) AB[(size_t)gr * 256 + col] = (__bf16)(acc[t][q] + bb);
            }
        }
    }
}

// ---- FUSED edge v9 (k_edge_p): wave-PAIR per receiver, h via LDS -----------
// Block = 4 waves = 2 receivers. The two waves of a receiver split the FIRST
// LAYER by k-half (computed once), write a double-buffered swizzled LDS
// h-tile, __syncthreads, then each wave MFMAs its COLUMN half reading af
// fragments ephemerally from LDS. No register spans the barrier.
__global__ __launch_bounds__(256) void k_edge_p(
    const __bf16* __restrict__ AB, const int* __restrict__ csr_s,
    const float* __restrict__ dist, const int* __restrict__ offs,
    const int* __restrict__ counts, const float* __restrict__ W2,
    const float* __restrict__ b2, const float* __restrict__ w3,
    float* __restrict__ aggr, int N)
{
    __shared__ __bf16 wt[128 * 128];          // 32 KB W2^T swizzled
    __shared__ float  w3s[128];
    __shared__ float  b2s[128];
    __shared__ __bf16 bsl[2][128];            // per-receiver B-row
    __shared__ __bf16 hd[2][2][16 * 128];     // [rcv][buf] h-tile, 16 KB
    for (int idx = threadIdx.x; idx < 128 * 128; idx += 256) {
        int j = idx & 127, k = idx >> 7;
        wt[(j << 7) + ((((k >> 3) ^ (j & 7))) << 3) + (k & 7)] = (__bf16)W2[(k << 7) + j];
    }
    for (int i = threadIdx.x; i < 128; i += 256) { w3s[i] = w3[i]; b2s[i] = b2[i]; }
    __syncthreads();

    const int lane = threadIdx.x & 63;
    const int row  = lane & 15;
    const int kq   = lane >> 4;
    const int wid  = threadIdx.x >> 6;
    const int rcv  = wid >> 1;                // which of the block's 2 receivers
    const int hf   = wid & 1;                 // column half (phase 2) = k-half (phase 1)
    const int r7   = row & 7;
    const int npair = (N + 1) >> 1;

    for (int p = blockIdx.x; p < npair; p += gridDim.x) {
        const int myr   = 2 * p + rcv;
        const bool valid = (myr < N);
        const int off = valid ? offs[myr]   : 0;
        const int deg = valid ? counts[myr] : 0;
        const int oth = 2 * p + (rcv ^ 1);
        const int dego = (oth < N) ? counts[oth] : 0;
        const int dmax = deg > dego ? deg : dego;
        const int ntb  = (dmax + 15) >> 4;    // same for all 4 waves

        if (hf == 0 && valid && lane < 16)
            *(bf16x8*)(&bsl[rcv][lane * 8]) =
                *(const bf16x8*)(AB + (size_t)myr * 256 + 128 + lane * 8);

        float colacc[4] = {0, 0, 0, 0};
        __syncthreads();                       // bsl ready; prev p done

        for (int tile = 0; tile < ntb; ++tile) {
            __bf16* hbuf = &hd[rcv][tile & 1][0];

            // ---- phase 1: my receiver, my K-HALF of the first layer -------
            {
                const int el = tile * 16 + row;
                const int cl = (deg > 0) ? ((el < deg) ? el : deg - 1) : 0;
                const int idx = (deg > 0) ? off + cl : 0;
                const int s   = csr_s[idx];
                const float d = dist[idx];
#pragma unroll
                for (int i = 0; i < 2; ++i) {
                    const int kb = hf * 8 + kq * 2 + i;   // 8-elem chunk index
                    const int k0 = kb * 8;
                    bf16x8 a  = *(const bf16x8*)(AB + (size_t)s * 256 + k0);
                    bf16x8 bb = *(const bf16x8*)(&bsl[rcv][k0]);
                    float4 w0 = *(const float4*)(w3s + k0);
                    float4 w1 = *(const float4*)(w3s + k0 + 4);
                    bf16x8 af;
                    af[0] = (__bf16)silu_f((float)a[0] + (float)bb[0] + d * w0.x);
                    af[1] = (__bf16)silu_f((float)a[1] + (float)bb[1] + d * w0.y);
                    af[2] = (__bf16)silu_f((float)a[2] + (float)bb[2] + d * w0.z);
                    af[3] = (__bf16)silu_f((float)a[3] + (float)bb[3] + d * w0.w);
                    af[4] = (__bf16)silu_f((float)a[4] + (float)bb[4] + d * w1.x);
                    af[5] = (__bf16)silu_f((float)a[5] + (float)bb[5] + d * w1.y);
                    af[6] = (__bf16)silu_f((float)a[6] + (float)bb[6] + d * w1.z);
                    af[7] = (__bf16)silu_f((float)a[7] + (float)bb[7] + d * w1.w);
                    *(bf16x8*)(hbuf + row * 128 + ((kb ^ r7) << 3)) = af;
                }
            }
            __syncthreads();                   // h-tile complete (both halves)

            // ---- phase 2: my COLUMN half over the full-k h-tile -----------
            f32x4 acc[4] = {};
#pragma unroll
            for (int c = 0; c < 4; ++c) {
                const int kb2 = c * 4 + kq;
                bf16x8 af = *(const bf16x8*)(hbuf + row * 128 + ((kb2 ^ r7) << 3));
#pragma unroll
                for (int t4 = 0; t4 < 4; ++t4) {
                    const int j  = (hf * 4 + t4) * 16 + row;
                    const int jb = j & 7;
                    bf16x8 b = *(const bf16x8*)(wt + (j << 7) + ((kb2 ^ jb) << 3));
                    acc[t4] = MFMA16(af, b, acc[t4], 0, 0, 0);
                }
            }
#pragma unroll
            for (int t4 = 0; t4 < 4; ++t4) {
                const float bb = b2s[(hf * 4 + t4) * 16 + row];
#pragma unroll
                for (int q = 0; q < 4; ++q) {
                    const int er = tile * 16 + kq * 4 + q;
                    if (er < deg) colacc[t4] += silu_f(acc[t4][q] + bb);
                }
            }
        }

#pragma unroll
        for (int t4 = 0; t4 < 4; ++t4) {
            float vv = colacc[t4];
            vv += __shfl_xor(vv, 16, 64);
            vv += __shfl_xor(vv, 32, 64);
            colacc[t4] = vv;
        }
        if (valid && kq == 0) {
#pragma unroll
            for (int t4 = 0; t4 < 4; ++t4)
                aggr[(size_t)myr * 128 + (hf * 4 + t4) * 16 + row] = colacc[t4];
        }
    }
}

// ---- FUSED edge v4 (fallback, 128 VGPR measured): column-split -------------
__global__ __launch_bounds__(256) void k_edge_f4(
    const __bf16* __restrict__ AB, const int* __restrict__ csr_s,
    const float* __restrict__ dist, const int* __restrict__ offs,
    const int* __restrict__ counts, const float* __restrict__ W2,
    const float* __restrict__ b2, const float* __restrict__ w3,
    float* __restrict__ aggr, int N)
{
    __shared__ __bf16 wt[128 * 128];
    __shared__ float  w3s[128];
    __shared__ float  b2s[128];
    __shared__ __bf16 bsl[4][128];
    for (int idx = threadIdx.x; idx < 128 * 128; idx += 256) {
        int j = idx & 127, k = idx >> 7;
        wt[(j << 7) + ((((k >> 3) ^ (j & 7))) << 3) + (k & 7)] = (__bf16)W2[(k << 7) + j];
    }
    for (int i = threadIdx.x; i < 128; i += 256) { w3s[i] = w3[i]; b2s[i] = b2[i]; }
    __syncthreads();

    const int lane = threadIdx.x & 63;
    const int row  = lane & 15;
    const int kq   = lane >> 4;
    const int wid  = threadIdx.x >> 6;
    const int wstep = gridDim.x * 4;
    const int nslot = 2 * N;

    for (int v = blockIdx.x * 4 + wid; v < nslot; v += wstep) {
        const int r  = v >> 1;
        const int hf = v & 1;
        const int off = offs[r];
        const int deg = counts[r];

        if (lane < 16)
            *(bf16x8*)(&bsl[wid][lane * 8]) =
                *(const bf16x8*)(AB + (size_t)r * 256 + 128 + lane * 8);

        float colacc[4] = {0, 0, 0, 0};

        const int ntile = (deg + 15) >> 4;
        for (int tile = 0; tile < ntile; ++tile) {
            const int el  = tile * 16 + row;
            const int idx = off + ((el < deg) ? el : (deg - 1));
            const int s   = csr_s[idx];
            const float d = dist[idx];

            f32x4 acc[4] = {};
#pragma unroll
            for (int c = 0; c < 4; ++c) {
                const int k0 = c * 32 + kq * 8;
                bf16x8 a  = *(const bf16x8*)(AB + (size_t)s * 256 + k0);
                bf16x8 bb = *(const bf16x8*)(&bsl[wid][k0]);
                float4 w0 = *(const float4*)(w3s + k0);
                float4 w1 = *(const float4*)(w3s + k0 + 4);
                bf16x8 af;
                af[0] = (__bf16)silu_f((float)a[0] + (float)bb[0] + d * w0.x);
                af[1] = (__bf16)silu_f((float)a[1] + (float)bb[1] + d * w0.y);
                af[2] = (__bf16)silu_f((float)a[2] + (float)bb[2] + d * w0.z);
                af[3] = (__bf16)silu_f((float)a[3] + (float)bb[3] + d * w0.w);
                af[4] = (__bf16)silu_f((float)a[4] + (float)bb[4] + d * w1.x);
                af[5] = (__bf16)silu_f((float)a[5] + (float)bb[5] + d * w1.y);
                af[6] = (__bf16)silu_f((float)a[6] + (float)bb[6] + d * w1.z);
                af[7] = (__bf16)silu_f((float)a[7] + (float)bb[7] + d * w1.w);
                const int kb = c * 4 + kq;
#pragma unroll
                for (int t4 = 0; t4 < 4; ++t4) {
                    const int j  = (hf * 4 + t4) * 16 + row;
                    const int jb = j & 7;
                    bf16x8 b = *(const bf16x8*)(wt + (j << 7) + ((kb ^ jb) << 3));
                    acc[t4] = MFMA16(af, b, acc[t4], 0, 0, 0);
                }
            }

#pragma unroll
            for (int t4 = 0; t4 < 4; ++t4) {
                const float bb = b2s[(hf * 4 + t4) * 16 + row];
#pragma unroll
                for (int q = 0; q < 4; ++q) {
                    const int er = tile * 16 + kq * 4 + q;
                    if (er < deg) colacc[t4] += silu_f(acc[t4][q] + bb);
                }
            }
        }

#pragma unroll
        for (int t4 = 0; t4 < 4; ++t4) {
            float vv = colacc[t4];
            vv += __shfl_xor(vv, 16, 64);
            vv += __shfl_xor(vv, 32, 64);
            colacc[t4] = vv;
        }
        if (kq == 0) {
#pragma unroll
            for (int t4 = 0; t4 < 4; ++t4)
                aggr[(size_t)r * 128 + (hf * 4 + t4) * 16 + row] = colacc[t4];
        }
    }
}

// -------- phase 3: u = silu(x@U1a + aggr@U1b + c1), bf16, IN PLACE over aggr
__global__ __launch_bounds__(256) void k_node2(
    const float* __restrict__ x, const float* __restrict__ aggr,
    const float* __restrict__ U1, const float* __restrict__ c1,
    __bf16* __restrict__ u, int N, int ngroups)
{
    __shared__ __bf16 wt[128 * 256];
    for (int idx = threadIdx.x; idx < 128 * 256; idx += 256) {
        int j = idx & 127, k = idx >> 7;
        wt[(j << 8) + ((((k >> 3) ^ (j & 7))) << 3) + (k & 7)] = (__bf16)U1[(k << 7) + j];
    }
    __syncthreads();

    const int lane = threadIdx.x & 63;
    const int row  = lane & 15;
    const int kq   = lane >> 4;

    for (int g = blockIdx.x; g < ngroups; g += gridDim.x) {
        const int row0 = g * 64 + (threadIdx.x >> 6) * 16;
        int m = row0 + row; if (m >= N) m = N - 1;

        bf16x8 afr[8];
#pragma unroll
        for (int c = 0; c < 8; ++c) {
            const int k0 = (c & 3) * 32 + kq * 8;
            const float* src = (c < 4) ? (x + (size_t)m * 128 + k0)
                                       : (aggr + (size_t)m * 128 + k0);
            float4 a0 = *(const float4*)(src);
            float4 a1 = *(const float4*)(src + 4);
            bf16x8 af;
            af[0]=(__bf16)a0.x; af[1]=(__bf16)a0.y; af[2]=(__bf16)a0.z; af[3]=(__bf16)a0.w;
            af[4]=(__bf16)a1.x; af[5]=(__bf16)a1.y; af[6]=(__bf16)a1.z; af[7]=(__bf16)a1.w;
            afr[c] = af;
        }

        f32x4 acc[8] = {};
#pragma unroll
        for (int t = 0; t < 8; ++t) {
            const int j  = t * 16 + row;
            const int jb = j & 7;
            const __bf16* base = wt + (j << 8);
#pragma unroll
            for (int c = 0; c < 8; ++c) {
                const int kb = c * 4 + kq;
                bf16x8 b = *(const bf16x8*)(base + ((kb ^ jb) << 3));
                acc[t] = MFMA16(afr[c], b, acc[t], 0, 0, 0);
            }
        }

#pragma unroll
        for (int t = 0; t < 8; ++t) {
            const int col = t * 16 + row;
            const float cc = c1[col];
#pragma unroll
            for (int q = 0; q < 4; ++q) {
                const int gr = row0 + kq * 4 + q;
                if (gr < N) u[(size_t)gr * 256 + col] = (__bf16)silu_f(acc[t][q] + cc);
            }
        }
    }
}

// ---------------- phase 4: out = u@U2 + c2 (overwrites AB in d_out) ---------
__global__ __launch_bounds__(256) void k_node3(
    const __bf16* __restrict__ u, const float* __restrict__ U2,
    const float* __restrict__ c2, float* __restrict__ out, int N, int ngroups)
{
    __shared__ __bf16 wt[128 * 128];
    for (int idx = threadIdx.x; idx < 128 * 128; idx += 256) {
        int j = idx & 127, k = idx >> 7;
        wt[(j << 7) + ((((k >> 3) ^ (j & 7))) << 3) + (k & 7)] = (__bf16)U2[(k << 7) + j];
    }
    __syncthreads();

    const int lane = threadIdx.x & 63;
    const int row  = lane & 15;
    const int kq   = lane >> 4;

    for (int g = blockIdx.x; g < ngroups; g += gridDim.x) {
        const int row0 = g * 64 + (threadIdx.x >> 6) * 16;
        int m = row0 + row; if (m >= N) m = N - 1;

        bf16x8 afr[4];
#pragma unroll
        for (int c = 0; c < 4; ++c) {
            const int k0 = c * 32 + kq * 8;
            afr[c] = *(const bf16x8*)(u + (size_t)m * 256 + k0);
        }

        f32x4 acc[8] = {};
#pragma unroll
        for (int t = 0; t < 8; ++t) {
            const int j  = t * 16 + row;
            const int jb = j & 7;
            const __bf16* base = wt + (j << 7);
#pragma unroll
            for (int c = 0; c < 4; ++c) {
                const int kb = c * 4 + kq;
                bf16x8 b = *(const bf16x8*)(base + ((kb ^ jb) << 3));
                acc[t] = MFMA16(afr[c], b, acc[t], 0, 0, 0);
            }
        }

#pragma unroll
        for (int t = 0; t < 8; ++t) {
            const int col = t * 16 + row;
            const float cc = c2[col];
#pragma unroll
            for (int q = 0; q < 4; ++q) {
                const int gr = row0 + kq * 4 + q;
                if (gr < N) out[(size_t)gr * 128 + col] = acc[t][q] + cc;
            }
        }
    }
}

extern "C" void kernel_launch(void* const* d_in, const int* in_sizes, int n_in,
                              void* d_out, int out_size, void* d_ws, size_t ws_size,
                              hipStream_t stream) {
    (void)n_in; (void)out_size;
    const float* x   = (const float*)d_in[0];
    const float* pos = (const float*)d_in[1];
    const int*   ei  = (const int*)d_in[2];
    const float* W1  = (const float*)d_in[3];
    const float* b1  = (const float*)d_in[4];
    const float* W2  = (const float*)d_in[5];
    const float* b2  = (const float*)d_in[6];
    const float* U1  = (const float*)d_in[7];
    const float* c1  = (const float*)d_in[8];
    const float* U2  = (const float*)d_in[9];
    const float* c2  = (const float*)d_in[10];

    const int N = in_sizes[0] / 128;
    const int E = in_sizes[2] / 2;

    // ---- workspace layout (16B-aligned slabs) ----
    const size_t aggr_b = (size_t)N * 128 * sizeof(float);
    const size_t Ni_b   = (((size_t)N * 4) + 15) & ~(size_t)15;
    const size_t E_b    = (((size_t)E * 4) + 15) & ~(size_t)15;
    size_t off = 0;
    char* base = (char*)d_ws;
    float* aggr   = (float*)(base + off); off += aggr_b;
    int*   flag   = (int*)  (base + off); off += 16;
    int*   counts = (int*)  (base + off); off += Ni_b;
    int*   offs   = (int*)  (base + off); off += Ni_b;
    int*   cursor = (int*)  (base + off); off += Ni_b;
    int*   parts  = (int*)  (base + off); off += 256 * 4;
    int*   csr_s  = (int*)  (base + off); off += E_b;
    int*   csr_r  = (int*)  (base + off); off += E_b;
    float* dist   = (float*)(base + off); off += E_b;
    const size_t need_csr = off;

    __bf16* u  = (__bf16*)d_ws;        // row stride 256 elem, aliases aggr
    __bf16* AB = (__bf16*)d_out;       // N*256 bf16 == out_nbytes

    const int nblk_scan = (N + 511) / 512;
    const bool csr_ok = (ws_size >= need_csr) && (nblk_scan <= 256);
    if (ws_size < aggr_b + 16 || !csr_ok) return;

    // calibrated selection (r16 ground truth: 128 regs = 4 waves/SIMD, good)
    hipFuncAttributes fap{};
    const bool use_p =
        (hipFuncGetAttributes(&fap, (const void*)k_edge_p) == hipSuccess) &&
        (fap.numRegs <= 128);

    const int ng_nodes = (N + 63) / 64;
    const int grid_n   = ng_nodes < 512 ? ng_nodes : 512;
    const int grid_E   = (E + 255) / 256;
    const int grid_Nt  = (N + 255) / 256;
    const int npair    = (N + 1) / 2;
    const int grid_p   = npair < 2048 ? npair : 2048;
    const int nslot    = 2 * N;
    const int grid_f4  = ((nslot + 3) / 4) < 2048 ? ((nslot + 3) / 4) : 2048;

    k_detect<<<1, 256, 0, stream>>>(ei, flag);
    k_node1<<<grid_n, 256, 0, stream>>>(x, W1, b1, AB, N, ng_nodes);

    hipMemsetAsync(counts, 0, (size_t)N * 4, stream);
    k_hist   <<<grid_E, 256, 0, stream>>>(ei, flag, counts, E);
    k_scan1  <<<nblk_scan, 256, 0, stream>>>(counts, offs, parts, N);
    k_scan2  <<<1, 256, 0, stream>>>(parts, nblk_scan);
    k_scan3  <<<grid_Nt, 256, 0, stream>>>(offs, parts, cursor, N);
    k_scatter<<<grid_E, 256, 0, stream>>>(ei, flag, pos, cursor,
                                          csr_s, csr_r, dist, E);

    if (use_p) {
        k_edge_p<<<grid_p, 256, 0, stream>>>(AB, csr_s, dist, offs, counts,
                                             W2, b2, W1 + 256 * 128, aggr, N);
    } else {
        k_edge_f4<<<grid_f4, 256, 0, stream>>>(AB, csr_s, dist, offs, counts,
                                               W2, b2, W1 + 256 * 128, aggr, N);
    }

    k_node2<<<grid_n, 256, 0, stream>>>(x, aggr, U1, c1, u, N, ng_nodes);
    k_node3<<<grid_n, 256, 0, stream>>>(u, U2, c2, (float*)d_out, N, ng_nodes);
}

// Round 20
// 352.789 us; speedup vs baseline: 1.1177x; 1.0279x over previous
//
#include <hip/hip_runtime.h>
#include <hip/hip_bf16.h>
#include <math.h>

typedef __bf16 bf16x8 __attribute__((ext_vector_type(8)));
typedef float  f32x4  __attribute__((ext_vector_type(4)));

#define MFMA16 __builtin_amdgcn_mfma_f32_16x16x32_bf16

__device__ __forceinline__ float silu_f(float v) {
    return v * __builtin_amdgcn_rcpf(1.0f + __expf(-v));
}

// LDS weight layout: Wt[j][k], bf16, 16B-chunk XOR swizzle:
// phys = j*K + (((k>>3) ^ (j&7))<<3) + (k&7)  -> ds_read_b128, 2-way max.

// ---- detector: is edge_index stored as int64 (odd words all zero)? ---------
__global__ void k_detect(const int* __restrict__ ei, int* __restrict__ flag) {
    __shared__ int red[256];
    int v = 0;
#pragma unroll
    for (int j = 0; j < 4; ++j) v |= ei[2 * (threadIdx.x * 4 + j) + 1];
    red[threadIdx.x] = v;
    __syncthreads();
    for (int s = 128; s > 0; s >>= 1) {
        if (threadIdx.x < s) red[threadIdx.x] |= red[threadIdx.x + s];
        __syncthreads();
    }
    if (threadIdx.x == 0) *flag = (red[0] == 0) ? 1 : 0;
}

// ---- CSR build --------------------------------------------------------------
__global__ __launch_bounds__(256) void k_hist(
    const int* __restrict__ ei, const int* __restrict__ flag,
    int* __restrict__ counts, int E)
{
    int e = blockIdx.x * 256 + threadIdx.x;
    if (e >= E) return;
    const int is64 = *flag;
    int r = is64 ? ei[2 * E + 2 * e] : ei[E + e];
    atomicAdd(&counts[r], 1);
}

__global__ __launch_bounds__(256) void k_scan1(
    const int* __restrict__ counts, int* __restrict__ offsets,
    int* __restrict__ partials, int N)
{
    __shared__ int pairv[256];
    __shared__ int buf[256];
    const int t = threadIdx.x;
    const int base = blockIdx.x * 512;
    int a = (base + 2 * t     < N) ? counts[base + 2 * t]     : 0;
    int b = (base + 2 * t + 1 < N) ? counts[base + 2 * t + 1] : 0;
    pairv[t] = a + b;
    buf[t]   = a + b;
    __syncthreads();
    for (int d = 1; d < 256; d <<= 1) {
        int v = buf[t];
        int w = (t >= d) ? buf[t - d] : 0;
        __syncthreads();
        buf[t] = v + w;
        __syncthreads();
    }
    int excl = buf[t] - pairv[t];
    if (base + 2 * t     < N) offsets[base + 2 * t]     = excl;
    if (base + 2 * t + 1 < N) offsets[base + 2 * t + 1] = excl + a;
    if (t == 255) partials[blockIdx.x] = buf[255];
}

__global__ void k_scan2(int* __restrict__ partials, int nblk) {
    __shared__ int buf[256];
    const int t = threadIdx.x;
    int v0 = (t < nblk) ? partials[t] : 0;
    buf[t] = v0;
    __syncthreads();
    for (int d = 1; d < 256; d <<= 1) {
        int v = buf[t];
        int w = (t >= d) ? buf[t - d] : 0;
        __syncthreads();
        buf[t] = v + w;
        __syncthreads();
    }
    if (t < nblk) partials[t] = buf[t] - v0;   // exclusive
}

__global__ __launch_bounds__(256) void k_scan3(
    int* __restrict__ offsets, const int* __restrict__ partials,
    int* __restrict__ cursor, int N)
{
    int i = blockIdx.x * 256 + threadIdx.x;
    if (i >= N) return;
    int v = offsets[i] + partials[i >> 9];
    offsets[i] = v;
    cursor[i]  = v;
}

// scatter + per-edge distance precompute (kills pos-gather chains downstream)
__global__ __launch_bounds__(256) void k_scatter(
    const int* __restrict__ ei, const int* __restrict__ flag,
    const float* __restrict__ pos, int* __restrict__ cursor,
    int* __restrict__ csr_s, int* __restrict__ csr_r,
    float* __restrict__ dist, int E)
{
    int e = blockIdx.x * 256 + threadIdx.x;
    if (e >= E) return;
    const int is64 = *flag;
    int s, r;
    if (is64) { s = ei[2 * e]; r = ei[2 * E + 2 * e]; }
    else      { s = ei[e];     r = ei[E + e];         }
    float dx = pos[3 * s]     - pos[3 * r];
    float dy = pos[3 * s + 1] - pos[3 * r + 1];
    float dz = pos[3 * s + 2] - pos[3 * r + 2];
    float d  = sqrtf(dx * dx + dy * dy + dz * dz);
    int slot = atomicAdd(&cursor[r], 1);
    csr_s[slot] = s;
    csr_r[slot] = r;
    dist[slot]  = d;
}

// ---- phase 1: AB[n][0:128]=bf16(x@W1a + b1), AB[n][128:256]=bf16(x@W1b) ----
__global__ __launch_bounds__(256) void k_node1(
    const float* __restrict__ x, const float* __restrict__ W1,
    const float* __restrict__ b1, __bf16* __restrict__ AB, int N, int ngroups)
{
    __shared__ __bf16 wt[256 * 128];
    for (int idx = threadIdx.x; idx < 256 * 128; idx += 256) {
        int j = idx & 255, k = idx >> 8;
        float w = (j < 128) ? W1[(k << 7) + j] : W1[((k + 128) << 7) + (j - 128)];
        wt[(j << 7) + ((((k >> 3) ^ (j & 7))) << 3) + (k & 7)] = (__bf16)w;
    }
    __syncthreads();

    const int lane = threadIdx.x & 63;
    const int row  = lane & 15;
    const int kq   = lane >> 4;

    for (int g = blockIdx.x; g < ngroups; g += gridDim.x) {
        const int row0 = g * 64 + (threadIdx.x >> 6) * 16;
        int m = row0 + row; if (m >= N) m = N - 1;
        const float* xr = x + (size_t)m * 128;

        bf16x8 afr[4];
#pragma unroll
        for (int c = 0; c < 4; ++c) {
            const int k0 = c * 32 + kq * 8;
            float4 a0 = *(const float4*)(xr + k0);
            float4 a1 = *(const float4*)(xr + k0 + 4);
            bf16x8 af;
            af[0]=(__bf16)a0.x; af[1]=(__bf16)a0.y; af[2]=(__bf16)a0.z; af[3]=(__bf16)a0.w;
            af[4]=(__bf16)a1.x; af[5]=(__bf16)a1.y; af[6]=(__bf16)a1.z; af[7]=(__bf16)a1.w;
            afr[c] = af;
        }

        f32x4 acc[16] = {};
#pragma unroll
        for (int t = 0; t < 16; ++t) {
            const int j  = t * 16 + row;
            const int jb = j & 7;
            const __bf16* base = wt + (j << 7);
#pragma unroll
            for (int c = 0; c < 4; ++c) {
                const int kb = c * 4 + kq;
                bf16x8 b = *(const bf16x8*)(base + ((kb ^ jb) << 3));
                acc[t] = MFMA16(afr[c], b, acc[t], 0, 0, 0);
            }
        }

#pragma unroll
        for (int t = 0; t < 16; ++t) {
            const int col = t * 16 + row;
            const float bb = (col < 128) ? b1[col] : 0.0f;
#pragma unroll
            for (int q = 0; q < 4; ++q) {
                const int gr = row0 + kq * 4 + q;
                if (gr < N) AB[(size_t)gr * 256 + col] = (__bf16)(acc[t][q] + bb);
            }
        }
    }
}

// ---- FUSED edge v10 (k_edge_p2): wave-pair per receiver + PREFETCH ---------
// Same cooperation as k_edge_p (first layer split by k-half, h via LDS), plus:
//  - next tile's s/d issued at phase-1 start; next A-chunks issued right
//    after the hd write -> gather latency hides under barrier+MFMA (we have
//    ~60 spare VGPRs at 68 base, so registers MAY span the barrier now).
//  - hd row stride padded to 136 elems (272B): provably even bank groups on
//    both the write (row+2kq+i) and read (row+4c+kq) patterns; XOR dropped.
__global__ __launch_bounds__(256) void k_edge_p2(
    const __bf16* __restrict__ AB, const int* __restrict__ csr_s,
    const float* __restrict__ dist, const int* __restrict__ offs,
    const int* __restrict__ counts, const float* __restrict__ W2,
    const float* __restrict__ b2, const float* __restrict__ w3,
    float* __restrict__ aggr, int N)
{
    __shared__ __bf16 wt[128 * 128];          // 32 KB W2^T swizzled
    __shared__ float  w3s[128];
    __shared__ float  b2s[128];
    __shared__ __bf16 bsl[2][128];            // per-receiver B-row
    __shared__ __bf16 hd[2][2][16 * 136];     // padded stride: 17 KB total
    for (int idx = threadIdx.x; idx < 128 * 128; idx += 256) {
        int j = idx & 127, k = idx >> 7;
        wt[(j << 7) + ((((k >> 3) ^ (j & 7))) << 3) + (k & 7)] = (__bf16)W2[(k << 7) + j];
    }
    for (int i = threadIdx.x; i < 128; i += 256) { w3s[i] = w3[i]; b2s[i] = b2[i]; }
    __syncthreads();

    const int lane = threadIdx.x & 63;
    const int row  = lane & 15;
    const int kq   = lane >> 4;
    const int wid  = threadIdx.x >> 6;
    const int rcv  = wid >> 1;
    const int hf   = wid & 1;
    const int npair = (N + 1) >> 1;

    for (int p = blockIdx.x; p < npair; p += gridDim.x) {
        const int myr   = 2 * p + rcv;
        const bool valid = (myr < N);
        const int off = valid ? offs[myr]   : 0;
        const int deg = valid ? counts[myr] : 0;
        const int oth = 2 * p + (rcv ^ 1);
        const int dego = (oth < N) ? counts[oth] : 0;
        const int dmax = deg > dego ? deg : dego;
        const int ntb  = (dmax + 15) >> 4;

        if (hf == 0 && valid && lane < 16)
            *(bf16x8*)(&bsl[rcv][lane * 8]) =
                *(const bf16x8*)(AB + (size_t)myr * 256 + 128 + lane * 8);

        float colacc[4] = {0, 0, 0, 0};

        // prefetch tile 0 (s, d, A-chunks for my k-half)
        int s_c = 0; float d_c = 0.0f;
        bf16x8 a_c0 = {}, a_c1 = {};
        if (ntb > 0) {
            const int cl  = (deg > 0) ? ((row < deg) ? row : deg - 1) : 0;
            const int idx = (deg > 0) ? off + cl : 0;
            s_c = csr_s[idx];
            d_c = dist[idx];
            const int kb0 = hf * 8 + kq * 2;
            a_c0 = *(const bf16x8*)(AB + (size_t)s_c * 256 + kb0 * 8);
            a_c1 = *(const bf16x8*)(AB + (size_t)s_c * 256 + (kb0 + 1) * 8);
        }
        __syncthreads();                       // bsl ready; prev p done

        for (int tile = 0; tile < ntb; ++tile) {
            __bf16* hbuf = &hd[rcv][tile & 1][0];

            // issue next tile's s/d loads FIRST (latency under this phase)
            int s_n = 0; float d_n = 0.0f;
            const bool more = (tile + 1 < ntb);
            if (more) {
                const int el2 = (tile + 1) * 16 + row;
                const int cl2 = (deg > 0) ? ((el2 < deg) ? el2 : deg - 1) : 0;
                const int idx2 = (deg > 0) ? off + cl2 : 0;
                s_n = csr_s[idx2];
                d_n = dist[idx2];
            }

            // ---- phase 1: my k-half of the first layer from prefetched A --
            {
                const int kb0 = hf * 8 + kq * 2;
#pragma unroll
                for (int i = 0; i < 2; ++i) {
                    const int kb = kb0 + i;
                    const int k0 = kb * 8;
                    bf16x8 a  = (i == 0) ? a_c0 : a_c1;
                    bf16x8 bb = *(const bf16x8*)(&bsl[rcv][k0]);
                    float4 w0 = *(const float4*)(w3s + k0);
                    float4 w1 = *(const float4*)(w3s + k0 + 4);
                    bf16x8 af;
                    af[0] = (__bf16)silu_f((float)a[0] + (float)bb[0] + d_c * w0.x);
                    af[1] = (__bf16)silu_f((float)a[1] + (float)bb[1] + d_c * w0.y);
                    af[2] = (__bf16)silu_f((float)a[2] + (float)bb[2] + d_c * w0.z);
                    af[3] = (__bf16)silu_f((float)a[3] + (float)bb[3] + d_c * w0.w);
                    af[4] = (__bf16)silu_f((float)a[4] + (float)bb[4] + d_c * w1.x);
                    af[5] = (__bf16)silu_f((float)a[5] + (float)bb[5] + d_c * w1.y);
                    af[6] = (__bf16)silu_f((float)a[6] + (float)bb[6] + d_c * w1.z);
                    af[7] = (__bf16)silu_f((float)a[7] + (float)bb[7] + d_c * w1.w);
                    *(bf16x8*)(hbuf + row * 136 + kb * 8) = af;
                }
            }

            // issue next tile's A loads (s_n has landed by now)
            if (more) {
                const int kb0 = hf * 8 + kq * 2;
                a_c0 = *(const bf16x8*)(AB + (size_t)s_n * 256 + kb0 * 8);
                a_c1 = *(const bf16x8*)(AB + (size_t)s_n * 256 + (kb0 + 1) * 8);
            }
            __syncthreads();                   // h-tile complete

            // ---- phase 2: my column half over the full-k h-tile -----------
            f32x4 acc[4] = {};
#pragma unroll
            for (int c = 0; c < 4; ++c) {
                const int kb2 = c * 4 + kq;
                bf16x8 af = *(const bf16x8*)(hbuf + row * 136 + kb2 * 8);
#pragma unroll
                for (int t4 = 0; t4 < 4; ++t4) {
                    const int j  = (hf * 4 + t4) * 16 + row;
                    const int jb = j & 7;
                    bf16x8 b = *(const bf16x8*)(wt + (j << 7) + ((kb2 ^ jb) << 3));
                    acc[t4] = MFMA16(af, b, acc[t4], 0, 0, 0);
                }
            }
#pragma unroll
            for (int t4 = 0; t4 < 4; ++t4) {
                const float bb = b2s[(hf * 4 + t4) * 16 + row];
#pragma unroll
                for (int q = 0; q < 4; ++q) {
                    const int er = tile * 16 + kq * 4 + q;
                    if (er < deg) colacc[t4] += silu_f(acc[t4][q] + bb);
                }
            }

            s_c = s_n; d_c = d_n;
        }

#pragma unroll
        for (int t4 = 0; t4 < 4; ++t4) {
            float vv = colacc[t4];
            vv += __shfl_xor(vv, 16, 64);
            vv += __shfl_xor(vv, 32, 64);
            colacc[t4] = vv;
        }
        if (valid && kq == 0) {
#pragma unroll
            for (int t4 = 0; t4 < 4; ++t4)
                aggr[(size_t)myr * 128 + (hf * 4 + t4) * 16 + row] = colacc[t4];
        }
    }
}

// ---- edge v9 fallback (68 VGPR measured, 205 us): wave-pair, no prefetch ---
__global__ __launch_bounds__(256) void k_edge_p(
    const __bf16* __restrict__ AB, const int* __restrict__ csr_s,
    const float* __restrict__ dist, const int* __restrict__ offs,
    const int* __restrict__ counts, const float* __restrict__ W2,
    const float* __restrict__ b2, const float* __restrict__ w3,
    float* __restrict__ aggr, int N)
{
    __shared__ __bf16 wt[128 * 128];
    __shared__ float  w3s[128];
    __shared__ float  b2s[128];
    __shared__ __bf16 bsl[2][128];
    __shared__ __bf16 hd[2][2][16 * 128];
    for (int idx = threadIdx.x; idx < 128 * 128; idx += 256) {
        int j = idx & 127, k = idx >> 7;
        wt[(j << 7) + ((((k >> 3) ^ (j & 7))) << 3) + (k & 7)] = (__bf16)W2[(k << 7) + j];
    }
    for (int i = threadIdx.x; i < 128; i += 256) { w3s[i] = w3[i]; b2s[i] = b2[i]; }
    __syncthreads();

    const int lane = threadIdx.x & 63;
    const int row  = lane & 15;
    const int kq   = lane >> 4;
    const int wid  = threadIdx.x >> 6;
    const int rcv  = wid >> 1;
    const int hf   = wid & 1;
    const int r7   = row & 7;
    const int npair = (N + 1) >> 1;

    for (int p = blockIdx.x; p < npair; p += gridDim.x) {
        const int myr   = 2 * p + rcv;
        const bool valid = (myr < N);
        const int off = valid ? offs[myr]   : 0;
        const int deg = valid ? counts[myr] : 0;
        const int oth = 2 * p + (rcv ^ 1);
        const int dego = (oth < N) ? counts[oth] : 0;
        const int dmax = deg > dego ? deg : dego;
        const int ntb  = (dmax + 15) >> 4;

        if (hf == 0 && valid && lane < 16)
            *(bf16x8*)(&bsl[rcv][lane * 8]) =
                *(const bf16x8*)(AB + (size_t)myr * 256 + 128 + lane * 8);

        float colacc[4] = {0, 0, 0, 0};
        __syncthreads();

        for (int tile = 0; tile < ntb; ++tile) {
            __bf16* hbuf = &hd[rcv][tile & 1][0];
            {
                const int el = tile * 16 + row;
                const int cl = (deg > 0) ? ((el < deg) ? el : deg - 1) : 0;
                const int idx = (deg > 0) ? off + cl : 0;
                const int s   = csr_s[idx];
                const float d = dist[idx];
#pragma unroll
                for (int i = 0; i < 2; ++i) {
                    const int kb = hf * 8 + kq * 2 + i;
                    const int k0 = kb * 8;
                    bf16x8 a  = *(const bf16x8*)(AB + (size_t)s * 256 + k0);
                    bf16x8 bb = *(const bf16x8*)(&bsl[rcv][k0]);
                    float4 w0 = *(const float4*)(w3s + k0);
                    float4 w1 = *(const float4*)(w3s + k0 + 4);
                    bf16x8 af;
                    af[0] = (__bf16)silu_f((float)a[0] + (float)bb[0] + d * w0.x);
                    af[1] = (__bf16)silu_f((float)a[1] + (float)bb[1] + d * w0.y);
                    af[2] = (__bf16)silu_f((float)a[2] + (float)bb[2] + d * w0.z);
                    af[3] = (__bf16)silu_f((float)a[3] + (float)bb[3] + d * w0.w);
                    af[4] = (__bf16)silu_f((float)a[4] + (float)bb[4] + d * w1.x);
                    af[5] = (__bf16)silu_f((float)a[5] + (float)bb[5] + d * w1.y);
                    af[6] = (__bf16)silu_f((float)a[6] + (float)bb[6] + d * w1.z);
                    af[7] = (__bf16)silu_f((float)a[7] + (float)bb[7] + d * w1.w);
                    *(bf16x8*)(hbuf + row * 128 + ((kb ^ r7) << 3)) = af;
                }
            }
            __syncthreads();

            f32x4 acc[4] = {};
#pragma unroll
            for (int c = 0; c < 4; ++c) {
                const int kb2 = c * 4 + kq;
                bf16x8 af = *(const bf16x8*)(hbuf + row * 128 + ((kb2 ^ r7) << 3));
#pragma unroll
                for (int t4 = 0; t4 < 4; ++t4) {
                    const int j  = (hf * 4 + t4) * 16 + row;
                    const int jb = j & 7;
                    bf16x8 b = *(const bf16x8*)(wt + (j << 7) + ((kb2 ^ jb) << 3));
                    acc[t4] = MFMA16(af, b, acc[t4], 0, 0, 0);
                }
            }
#pragma unroll
            for (int t4 = 0; t4 < 4; ++t4) {
                const float bb = b2s[(hf * 4 + t4) * 16 + row];
#pragma unroll
                for (int q = 0; q < 4; ++q) {
                    const int er = tile * 16 + kq * 4 + q;
                    if (er < deg) colacc[t4] += silu_f(acc[t4][q] + bb);
                }
            }
        }

#pragma unroll
        for (int t4 = 0; t4 < 4; ++t4) {
            float vv = colacc[t4];
            vv += __shfl_xor(vv, 16, 64);
            vv += __shfl_xor(vv, 32, 64);
            colacc[t4] = vv;
        }
        if (valid && kq == 0) {
#pragma unroll
            for (int t4 = 0; t4 < 4; ++t4)
                aggr[(size_t)myr * 128 + (hf * 4 + t4) * 16 + row] = colacc[t4];
        }
    }
}

// -------- phase 3: u = silu(x@U1a + aggr@U1b + c1), bf16, IN PLACE over aggr
__global__ __launch_bounds__(256) void k_node2(
    const float* __restrict__ x, const float* __restrict__ aggr,
    const float* __restrict__ U1, const float* __restrict__ c1,
    __bf16* __restrict__ u, int N, int ngroups)
{
    __shared__ __bf16 wt[128 * 256];
    for (int idx = threadIdx.x; idx < 128 * 256; idx += 256) {
        int j = idx & 127, k = idx >> 7;
        wt[(j << 8) + ((((k >> 3) ^ (j & 7))) << 3) + (k & 7)] = (__bf16)U1[(k << 7) + j];
    }
    __syncthreads();

    const int lane = threadIdx.x & 63;
    const int row  = lane & 15;
    const int kq   = lane >> 4;

    for (int g = blockIdx.x; g < ngroups; g += gridDim.x) {
        const int row0 = g * 64 + (threadIdx.x >> 6) * 16;
        int m = row0 + row; if (m >= N) m = N - 1;

        bf16x8 afr[8];
#pragma unroll
        for (int c = 0; c < 8; ++c) {
            const int k0 = (c & 3) * 32 + kq * 8;
            const float* src = (c < 4) ? (x + (size_t)m * 128 + k0)
                                       : (aggr + (size_t)m * 128 + k0);
            float4 a0 = *(const float4*)(src);
            float4 a1 = *(const float4*)(src + 4);
            bf16x8 af;
            af[0]=(__bf16)a0.x; af[1]=(__bf16)a0.y; af[2]=(__bf16)a0.z; af[3]=(__bf16)a0.w;
            af[4]=(__bf16)a1.x; af[5]=(__bf16)a1.y; af[6]=(__bf16)a1.z; af[7]=(__bf16)a1.w;
            afr[c] = af;
        }

        f32x4 acc[8] = {};
#pragma unroll
        for (int t = 0; t < 8; ++t) {
            const int j  = t * 16 + row;
            const int jb = j & 7;
            const __bf16* base = wt + (j << 8);
#pragma unroll
            for (int c = 0; c < 8; ++c) {
                const int kb = c * 4 + kq;
                bf16x8 b = *(const bf16x8*)(base + ((kb ^ jb) << 3));
                acc[t] = MFMA16(afr[c], b, acc[t], 0, 0, 0);
            }
        }

#pragma unroll
        for (int t = 0; t < 8; ++t) {
            const int col = t * 16 + row;
            const float cc = c1[col];
#pragma unroll
            for (int q = 0; q < 4; ++q) {
                const int gr = row0 + kq * 4 + q;
                if (gr < N) u[(size_t)gr * 256 + col] = (__bf16)silu_f(acc[t][q] + cc);
            }
        }
    }
}

// ---------------- phase 4: out = u@U2 + c2 (overwrites AB in d_out) ---------
__global__ __launch_bounds__(256) void k_node3(
    const __bf16* __restrict__ u, const float* __restrict__ U2,
    const float* __restrict__ c2, float* __restrict__ out, int N, int ngroups)
{
    __shared__ __bf16 wt[128 * 128];
    for (int idx = threadIdx.x; idx < 128 * 128; idx += 256) {
        int j = idx & 127, k = idx >> 7;
        wt[(j << 7) + ((((k >> 3) ^ (j & 7))) << 3) + (k & 7)] = (__bf16)U2[(k << 7) + j];
    }
    __syncthreads();

    const int lane = threadIdx.x & 63;
    const int row  = lane & 15;
    const int kq   = lane >> 4;

    for (int g = blockIdx.x; g < ngroups; g += gridDim.x) {
        const int row0 = g * 64 + (threadIdx.x >> 6) * 16;
        int m = row0 + row; if (m >= N) m = N - 1;

        bf16x8 afr[4];
#pragma unroll
        for (int c = 0; c < 4; ++c) {
            const int k0 = c * 32 + kq * 8;
            afr[c] = *(const bf16x8*)(u + (size_t)m * 256 + k0);
        }

        f32x4 acc[8] = {};
#pragma unroll
        for (int t = 0; t < 8; ++t) {
            const int j  = t * 16 + row;
            const int jb = j & 7;
            const __bf16* base = wt + (j << 7);
#pragma unroll
            for (int c = 0; c < 4; ++c) {
                const int kb = c * 4 + kq;
                bf16x8 b = *(const bf16x8*)(base + ((kb ^ jb) << 3));
                acc[t] = MFMA16(afr[c], b, acc[t], 0, 0, 0);
            }
        }

#pragma unroll
        for (int t = 0; t < 8; ++t) {
            const int col = t * 16 + row;
            const float cc = c2[col];
#pragma unroll
            for (int q = 0; q < 4; ++q) {
                const int gr = row0 + kq * 4 + q;
                if (gr < N) out[(size_t)gr * 128 + col] = acc[t][q] + cc;
            }
        }
    }
}

extern "C" void kernel_launch(void* const* d_in, const int* in_sizes, int n_in,
                              void* d_out, int out_size, void* d_ws, size_t ws_size,
                              hipStream_t stream) {
    (void)n_in; (void)out_size;
    const float* x   = (const float*)d_in[0];
    const float* pos = (const float*)d_in[1];
    const int*   ei  = (const int*)d_in[2];
    const float* W1  = (const float*)d_in[3];
    const float* b1  = (const float*)d_in[4];
    const float* W2  = (const float*)d_in[5];
    const float* b2  = (const float*)d_in[6];
    const float* U1  = (const float*)d_in[7];
    const float* c1  = (const float*)d_in[8];
    const float* U2  = (const float*)d_in[9];
    const float* c2  = (const float*)d_in[10];

    const int N = in_sizes[0] / 128;
    const int E = in_sizes[2] / 2;

    // ---- workspace layout (16B-aligned slabs) ----
    const size_t aggr_b = (size_t)N * 128 * sizeof(float);
    const size_t Ni_b   = (((size_t)N * 4) + 15) & ~(size_t)15;
    const size_t E_b    = (((size_t)E * 4) + 15) & ~(size_t)15;
    size_t off = 0;
    char* base = (char*)d_ws;
    float* aggr   = (float*)(base + off); off += aggr_b;
    int*   flag   = (int*)  (base + off); off += 16;
    int*   counts = (int*)  (base + off); off += Ni_b;
    int*   offs   = (int*)  (base + off); off += Ni_b;
    int*   cursor = (int*)  (base + off); off += Ni_b;
    int*   parts  = (int*)  (base + off); off += 256 * 4;
    int*   csr_s  = (int*)  (base + off); off += E_b;
    int*   csr_r  = (int*)  (base + off); off += E_b;
    float* dist   = (float*)(base + off); off += E_b;
    const size_t need_csr = off;

    __bf16* u  = (__bf16*)d_ws;        // row stride 256 elem, aliases aggr
    __bf16* AB = (__bf16*)d_out;       // N*256 bf16 == out_nbytes

    const int nblk_scan = (N + 511) / 512;
    const bool csr_ok = (ws_size >= need_csr) && (nblk_scan <= 256);
    if (ws_size < aggr_b + 16 || !csr_ok) return;

    // calibrated selection (r16 ground truth: <=128 regs = 4 waves/SIMD ok)
    hipFuncAttributes fa2{};
    const bool use_p2 =
        (hipFuncGetAttributes(&fa2, (const void*)k_edge_p2) == hipSuccess) &&
        (fa2.numRegs <= 128);

    const int ng_nodes = (N + 63) / 64;
    const int grid_n   = ng_nodes < 512 ? ng_nodes : 512;
    const int grid_E   = (E + 255) / 256;
    const int grid_Nt  = (N + 255) / 256;
    const int npair    = (N + 1) / 2;
    const int grid_p   = npair < 2048 ? npair : 2048;

    k_detect<<<1, 256, 0, stream>>>(ei, flag);
    k_node1<<<grid_n, 256, 0, stream>>>(x, W1, b1, AB, N, ng_nodes);

    hipMemsetAsync(counts, 0, (size_t)N * 4, stream);
    k_hist   <<<grid_E, 256, 0, stream>>>(ei, flag, counts, E);
    k_scan1  <<<nblk_scan, 256, 0, stream>>>(counts, offs, parts, N);
    k_scan2  <<<1, 256, 0, stream>>>(parts, nblk_scan);
    k_scan3  <<<grid_Nt, 256, 0, stream>>>(offs, parts, cursor, N);
    k_scatter<<<grid_E, 256, 0, stream>>>(ei, flag, pos, cursor,
                                          csr_s, csr_r, dist, E);

    if (use_p2) {
        k_edge_p2<<<grid_p, 256, 0, stream>>>(AB, csr_s, dist, offs, counts,
                                              W2, b2, W1 + 256 * 128, aggr, N);
    } else {
        k_edge_p<<<grid_p, 256, 0, stream>>>(AB, csr_s, dist, offs, counts,
                                             W2, b2, W1 + 256 * 128, aggr, N);
    }

    k_node2<<<grid_n, 256, 0, stream>>>(x, aggr, U1, c1, u, N, ng_nodes);
    k_node3<<<grid_n, 256, 0, stream>>>(u, U2, c2, (float*)d_out, N, ng_nodes);
}

// Round 21
// 326.172 us; speedup vs baseline: 1.2089x; 1.0816x over previous
//
#include <hip/hip_runtime.h>
#include <hip/hip_bf16.h>
#include <math.h>

typedef __bf16 bf16x8 __attribute__((ext_vector_type(8)));
typedef float  f32x4  __attribute__((ext_vector_type(4)));

#define MFMA16 __builtin_amdgcn_mfma_f32_16x16x32_bf16

__device__ __forceinline__ float silu_f(float v) {
    return v * __builtin_amdgcn_rcpf(1.0f + __expf(-v));
}

// LDS weight layout: Wt[j][k], bf16, 16B-chunk XOR swizzle:
// phys = j*K + (((k>>3) ^ (j&7))<<3) + (k&7)  -> ds_read_b128, 2-way max.

// ---- detector: is edge_index stored as int64 (odd words all zero)? ---------
__global__ void k_detect(const int* __restrict__ ei, int* __restrict__ flag) {
    __shared__ int red[256];
    int v = 0;
#pragma unroll
    for (int j = 0; j < 4; ++j) v |= ei[2 * (threadIdx.x * 4 + j) + 1];
    red[threadIdx.x] = v;
    __syncthreads();
    for (int s = 128; s > 0; s >>= 1) {
        if (threadIdx.x < s) red[threadIdx.x] |= red[threadIdx.x + s];
        __syncthreads();
    }
    if (threadIdx.x == 0) *flag = (red[0] == 0) ? 1 : 0;
}

// ---- CSR build --------------------------------------------------------------
__global__ __launch_bounds__(256) void k_hist(
    const int* __restrict__ ei, const int* __restrict__ flag,
    int* __restrict__ counts, int E)
{
    int e = blockIdx.x * 256 + threadIdx.x;
    if (e >= E) return;
    const int is64 = *flag;
    int r = is64 ? ei[2 * E + 2 * e] : ei[E + e];
    atomicAdd(&counts[r], 1);
}

__global__ __launch_bounds__(256) void k_scan1(
    const int* __restrict__ counts, int* __restrict__ offsets,
    int* __restrict__ partials, int N)
{
    __shared__ int pairv[256];
    __shared__ int buf[256];
    const int t = threadIdx.x;
    const int base = blockIdx.x * 512;
    int a = (base + 2 * t     < N) ? counts[base + 2 * t]     : 0;
    int b = (base + 2 * t + 1 < N) ? counts[base + 2 * t + 1] : 0;
    pairv[t] = a + b;
    buf[t]   = a + b;
    __syncthreads();
    for (int d = 1; d < 256; d <<= 1) {
        int v = buf[t];
        int w = (t >= d) ? buf[t - d] : 0;
        __syncthreads();
        buf[t] = v + w;
        __syncthreads();
    }
    int excl = buf[t] - pairv[t];
    if (base + 2 * t     < N) offsets[base + 2 * t]     = excl;
    if (base + 2 * t + 1 < N) offsets[base + 2 * t + 1] = excl + a;
    if (t == 255) partials[blockIdx.x] = buf[255];
}

__global__ void k_scan2(int* __restrict__ partials, int nblk) {
    __shared__ int buf[256];
    const int t = threadIdx.x;
    int v0 = (t < nblk) ? partials[t] : 0;
    buf[t] = v0;
    __syncthreads();
    for (int d = 1; d < 256; d <<= 1) {
        int v = buf[t];
        int w = (t >= d) ? buf[t - d] : 0;
        __syncthreads();
        buf[t] = v + w;
        __syncthreads();
    }
    if (t < nblk) partials[t] = buf[t] - v0;   // exclusive
}

__global__ __launch_bounds__(256) void k_scan3(
    int* __restrict__ offsets, const int* __restrict__ partials,
    int* __restrict__ cursor, int N)
{
    int i = blockIdx.x * 256 + threadIdx.x;
    if (i >= N) return;
    int v = offsets[i] + partials[i >> 9];
    offsets[i] = v;
    cursor[i]  = v;
}

// scatter + per-edge distance precompute (kills pos-gather chains downstream)
__global__ __launch_bounds__(256) void k_scatter(
    const int* __restrict__ ei, const int* __restrict__ flag,
    const float* __restrict__ pos, int* __restrict__ cursor,
    int* __restrict__ csr_s, int* __restrict__ csr_r,
    float* __restrict__ dist, int E)
{
    int e = blockIdx.x * 256 + threadIdx.x;
    if (e >= E) return;
    const int is64 = *flag;
    int s, r;
    if (is64) { s = ei[2 * e]; r = ei[2 * E + 2 * e]; }
    else      { s = ei[e];     r = ei[E + e];         }
    float dx = pos[3 * s]     - pos[3 * r];
    float dy = pos[3 * s + 1] - pos[3 * r + 1];
    float dz = pos[3 * s + 2] - pos[3 * r + 2];
    float d  = sqrtf(dx * dx + dy * dy + dz * dz);
    int slot = atomicAdd(&cursor[r], 1);
    csr_s[slot] = s;
    csr_r[slot] = r;
    dist[slot]  = d;
}

// ---- phase 1: AB[n][0:128]=bf16(x@W1a + b1), AB[n][128:256]=bf16(x@W1b) ----
__global__ __launch_bounds__(256) void k_node1(
    const float* __restrict__ x, const float* __restrict__ W1,
    const float* __restrict__ b1, __bf16* __restrict__ AB, int N, int ngroups)
{
    __shared__ __bf16 wt[256 * 128];
    for (int idx = threadIdx.x; idx < 256 * 128; idx += 256) {
        int j = idx & 255, k = idx >> 8;
        float w = (j < 128) ? W1[(k << 7) + j] : W1[((k + 128) << 7) + (j - 128)];
        wt[(j << 7) + ((((k >> 3) ^ (j & 7))) << 3) + (k & 7)] = (__bf16)w;
    }
    __syncthreads();

    const int lane = threadIdx.x & 63;
    const int row  = lane & 15;
    const int kq   = lane >> 4;

    for (int g = blockIdx.x; g < ngroups; g += gridDim.x) {
        const int row0 = g * 64 + (threadIdx.x >> 6) * 16;
        int m = row0 + row; if (m >= N) m = N - 1;
        const float* xr = x + (size_t)m * 128;

        bf16x8 afr[4];
#pragma unroll
        for (int c = 0; c < 4; ++c) {
            const int k0 = c * 32 + kq * 8;
            float4 a0 = *(const float4*)(xr + k0);
            float4 a1 = *(const float4*)(xr + k0 + 4);
            bf16x8 af;
            af[0]=(__bf16)a0.x; af[1]=(__bf16)a0.y; af[2]=(__bf16)a0.z; af[3]=(__bf16)a0.w;
            af[4]=(__bf16)a1.x; af[5]=(__bf16)a1.y; af[6]=(__bf16)a1.z; af[7]=(__bf16)a1.w;
            afr[c] = af;
        }

        f32x4 acc[16] = {};
#pragma unroll
        for (int t = 0; t < 16; ++t) {
            const int j  = t * 16 + row;
            const int jb = j & 7;
            const __bf16* base = wt + (j << 7);
#pragma unroll
            for (int c = 0; c < 4; ++c) {
                const int kb = c * 4 + kq;
                bf16x8 b = *(const bf16x8*)(base + ((kb ^ jb) << 3));
                acc[t] = MFMA16(afr[c], b, acc[t], 0, 0, 0);
            }
        }

#pragma unroll
        for (int t = 0; t < 16; ++t) {
            const int col = t * 16 + row;
            const float bb = (col < 128) ? b1[col] : 0.0f;
#pragma unroll
            for (int q = 0; q < 4; ++q) {
                const int gr = row0 + kq * 4 + q;
                if (gr < N) AB[(size_t)gr * 256 + col] = (__bf16)(acc[t][q] + bb);
            }
        }
    }
}

// ---- FUSED edge v11 (k_edge_p3): wave-pair per RECEIVER-PAIR window --------
// r0,r1 adjacent in CSR -> combined contiguous edge window of deg0+deg1 edges
// packed into ceil(sum/16) tiles (cuts the per-receiver ceil padding from
// ~64% to ~30%). Rows may mix receivers: first layer selects bsl[ps][rsel]
// per row; epilogue keeps two masked colacc sets; both receivers written.
__global__ __launch_bounds__(256) void k_edge_p3(
    const __bf16* __restrict__ AB, const int* __restrict__ csr_s,
    const float* __restrict__ dist, const int* __restrict__ offs,
    const int* __restrict__ counts, const float* __restrict__ W2,
    const float* __restrict__ b2, const float* __restrict__ w3,
    float* __restrict__ aggr, int N)
{
    __shared__ __bf16 wt[128 * 128];          // 32 KB W2^T swizzled
    __shared__ float  w3s[128];
    __shared__ float  b2s[128];
    __shared__ __bf16 bsl[2][2][128];         // [pair-slot][rcv-of-pair] B-row
    __shared__ __bf16 hd[2][2][16 * 136];     // [pair-slot][buf] padded h-tile
    for (int idx = threadIdx.x; idx < 128 * 128; idx += 256) {
        int j = idx & 127, k = idx >> 7;
        wt[(j << 7) + ((((k >> 3) ^ (j & 7))) << 3) + (k & 7)] = (__bf16)W2[(k << 7) + j];
    }
    for (int i = threadIdx.x; i < 128; i += 256) { w3s[i] = w3[i]; b2s[i] = b2[i]; }
    __syncthreads();

    const int lane = threadIdx.x & 63;
    const int row  = lane & 15;
    const int kq   = lane >> 4;
    const int wid  = threadIdx.x >> 6;
    const int ps   = wid >> 1;                // pair-slot (2 per block)
    const int hf   = wid & 1;                 // column half / k-half
    const int nquad = (N + 3) >> 2;

    for (int Q = blockIdx.x; Q < nquad; Q += gridDim.x) {
        const int r0 = 4 * Q + 2 * ps;
        const int r1 = r0 + 1;
        const bool v0 = (r0 < N), v1 = (r1 < N);
        const int w0   = v0 ? offs[r0]   : 0;
        const int deg0 = v0 ? counts[r0] : 0;
        const int deg1 = v1 ? counts[r1] : 0;
        const int degsum = deg0 + deg1;
        // other pair-slot's combined degree -> block-uniform tile count
        const int o0  = 4 * Q + 2 * (ps ^ 1);
        const int od0 = (o0 < N)     ? counts[o0]     : 0;
        const int od1 = (o0 + 1 < N) ? counts[o0 + 1] : 0;
        const int osum = od0 + od1;
        const int msum = degsum > osum ? degsum : osum;
        const int ntb  = (msum + 15) >> 4;

        // stage both B rows: hf==0 wave, lanes 0-15 -> r0, lanes 16-31 -> r1
        if (hf == 0 && lane < 32) {
            const int which = lane >> 4;
            const int rr = r0 + which;
            if (rr < N)
                *(bf16x8*)(&bsl[ps][which][(lane & 15) * 8]) =
                    *(const bf16x8*)(AB + (size_t)rr * 256 + 128 + (lane & 15) * 8);
        }

        float ca0[4] = {0, 0, 0, 0};
        float ca1[4] = {0, 0, 0, 0};

        // prefetch tile 0 (s, d, receiver-select, A-chunks for my k-half)
        float d_c = 0.0f; int rs_c = 0;
        bf16x8 a_c0 = {}, a_c1 = {};
        if (ntb > 0) {
            const int cl = (degsum > 0) ? ((row < degsum) ? row : degsum - 1) : 0;
            const int gi = (degsum > 0) ? w0 + cl : 0;
            const int s0 = csr_s[gi];
            d_c  = dist[gi];
            rs_c = (degsum > 0 && cl >= deg0) ? 1 : 0;
            const int kb0 = hf * 8 + kq * 2;
            a_c0 = *(const bf16x8*)(AB + (size_t)s0 * 256 + kb0 * 8);
            a_c1 = *(const bf16x8*)(AB + (size_t)s0 * 256 + (kb0 + 1) * 8);
        }
        __syncthreads();                       // bsl ready; prev Q done

        for (int tile = 0; tile < ntb; ++tile) {
            __bf16* hbuf = &hd[ps][tile & 1][0];

            // issue next tile's s/d/rsel loads first
            int s_n = 0; float d_n = 0.0f; int rs_n = 0;
            const bool more = (tile + 1 < ntb);
            if (more) {
                const int el2 = (tile + 1) * 16 + row;
                const int cl2 = (degsum > 0) ? ((el2 < degsum) ? el2 : degsum - 1) : 0;
                const int gi2 = (degsum > 0) ? w0 + cl2 : 0;
                s_n  = csr_s[gi2];
                d_n  = dist[gi2];
                rs_n = (degsum > 0 && cl2 >= deg0) ? 1 : 0;
            }

            // ---- phase 1: my k-half of the first layer (prefetched A) -----
            {
                const int kb0 = hf * 8 + kq * 2;
#pragma unroll
                for (int i = 0; i < 2; ++i) {
                    const int kb = kb0 + i;
                    const int k0 = kb * 8;
                    bf16x8 a  = (i == 0) ? a_c0 : a_c1;
                    bf16x8 bb = *(const bf16x8*)(&bsl[ps][rs_c][k0]);
                    float4 w0f = *(const float4*)(w3s + k0);
                    float4 w1f = *(const float4*)(w3s + k0 + 4);
                    bf16x8 af;
                    af[0] = (__bf16)silu_f((float)a[0] + (float)bb[0] + d_c * w0f.x);
                    af[1] = (__bf16)silu_f((float)a[1] + (float)bb[1] + d_c * w0f.y);
                    af[2] = (__bf16)silu_f((float)a[2] + (float)bb[2] + d_c * w0f.z);
                    af[3] = (__bf16)silu_f((float)a[3] + (float)bb[3] + d_c * w0f.w);
                    af[4] = (__bf16)silu_f((float)a[4] + (float)bb[4] + d_c * w1f.x);
                    af[5] = (__bf16)silu_f((float)a[5] + (float)bb[5] + d_c * w1f.y);
                    af[6] = (__bf16)silu_f((float)a[6] + (float)bb[6] + d_c * w1f.z);
                    af[7] = (__bf16)silu_f((float)a[7] + (float)bb[7] + d_c * w1f.w);
                    *(bf16x8*)(hbuf + row * 136 + kb * 8) = af;
                }
            }

            // issue next tile's A loads
            if (more) {
                const int kb0 = hf * 8 + kq * 2;
                a_c0 = *(const bf16x8*)(AB + (size_t)s_n * 256 + kb0 * 8);
                a_c1 = *(const bf16x8*)(AB + (size_t)s_n * 256 + (kb0 + 1) * 8);
            }
            __syncthreads();                   // h-tile complete

            // ---- phase 2: my column half over the full-k h-tile -----------
            f32x4 acc[4] = {};
#pragma unroll
            for (int c = 0; c < 4; ++c) {
                const int kb2 = c * 4 + kq;
                bf16x8 af = *(const bf16x8*)(hbuf + row * 136 + kb2 * 8);
#pragma unroll
                for (int t4 = 0; t4 < 4; ++t4) {
                    const int j  = (hf * 4 + t4) * 16 + row;
                    const int jb = j & 7;
                    bf16x8 b = *(const bf16x8*)(wt + (j << 7) + ((kb2 ^ jb) << 3));
                    acc[t4] = MFMA16(af, b, acc[t4], 0, 0, 0);
                }
            }
#pragma unroll
            for (int t4 = 0; t4 < 4; ++t4) {
                const float bb = b2s[(hf * 4 + t4) * 16 + row];
#pragma unroll
                for (int q = 0; q < 4; ++q) {
                    const int er = tile * 16 + kq * 4 + q;   // combined window
                    if (er < degsum) {
                        float v = silu_f(acc[t4][q] + bb);
                        if (er < deg0) ca0[t4] += v; else ca1[t4] += v;
                    }
                }
            }

            d_c = d_n; rs_c = rs_n;
        }

        // reduce k-quarters + write both receivers' column halves
#pragma unroll
        for (int t4 = 0; t4 < 4; ++t4) {
            float u0 = ca0[t4], u1 = ca1[t4];
            u0 += __shfl_xor(u0, 16, 64); u0 += __shfl_xor(u0, 32, 64);
            u1 += __shfl_xor(u1, 16, 64); u1 += __shfl_xor(u1, 32, 64);
            ca0[t4] = u0; ca1[t4] = u1;
        }
        if (kq == 0) {
#pragma unroll
            for (int t4 = 0; t4 < 4; ++t4) {
                if (v0) aggr[(size_t)r0 * 128 + (hf * 4 + t4) * 16 + row] = ca0[t4];
                if (v1) aggr[(size_t)r1 * 128 + (hf * 4 + t4) * 16 + row] = ca1[t4];
            }
        }
    }
}

// ---- edge v10 fallback (68 VGPR measured, 198 us): wave-pair + prefetch ----
__global__ __launch_bounds__(256) void k_edge_p2(
    const __bf16* __restrict__ AB, const int* __restrict__ csr_s,
    const float* __restrict__ dist, const int* __restrict__ offs,
    const int* __restrict__ counts, const float* __restrict__ W2,
    const float* __restrict__ b2, const float* __restrict__ w3,
    float* __restrict__ aggr, int N)
{
    __shared__ __bf16 wt[128 * 128];
    __shared__ float  w3s[128];
    __shared__ float  b2s[128];
    __shared__ __bf16 bsl[2][128];
    __shared__ __bf16 hd[2][2][16 * 136];
    for (int idx = threadIdx.x; idx < 128 * 128; idx += 256) {
        int j = idx & 127, k = idx >> 7;
        wt[(j << 7) + ((((k >> 3) ^ (j & 7))) << 3) + (k & 7)] = (__bf16)W2[(k << 7) + j];
    }
    for (int i = threadIdx.x; i < 128; i += 256) { w3s[i] = w3[i]; b2s[i] = b2[i]; }
    __syncthreads();

    const int lane = threadIdx.x & 63;
    const int row  = lane & 15;
    const int kq   = lane >> 4;
    const int wid  = threadIdx.x >> 6;
    const int rcv  = wid >> 1;
    const int hf   = wid & 1;
    const int npair = (N + 1) >> 1;

    for (int p = blockIdx.x; p < npair; p += gridDim.x) {
        const int myr   = 2 * p + rcv;
        const bool valid = (myr < N);
        const int off = valid ? offs[myr]   : 0;
        const int deg = valid ? counts[myr] : 0;
        const int oth = 2 * p + (rcv ^ 1);
        const int dego = (oth < N) ? counts[oth] : 0;
        const int dmax = deg > dego ? deg : dego;
        const int ntb  = (dmax + 15) >> 4;

        if (hf == 0 && valid && lane < 16)
            *(bf16x8*)(&bsl[rcv][lane * 8]) =
                *(const bf16x8*)(AB + (size_t)myr * 256 + 128 + lane * 8);

        float colacc[4] = {0, 0, 0, 0};

        int s_c = 0; float d_c = 0.0f;
        bf16x8 a_c0 = {}, a_c1 = {};
        if (ntb > 0) {
            const int cl  = (deg > 0) ? ((row < deg) ? row : deg - 1) : 0;
            const int idx = (deg > 0) ? off + cl : 0;
            s_c = csr_s[idx];
            d_c = dist[idx];
            const int kb0 = hf * 8 + kq * 2;
            a_c0 = *(const bf16x8*)(AB + (size_t)s_c * 256 + kb0 * 8);
            a_c1 = *(const bf16x8*)(AB + (size_t)s_c * 256 + (kb0 + 1) * 8);
        }
        __syncthreads();

        for (int tile = 0; tile < ntb; ++tile) {
            __bf16* hbuf = &hd[rcv][tile & 1][0];

            int s_n = 0; float d_n = 0.0f;
            const bool more = (tile + 1 < ntb);
            if (more) {
                const int el2 = (tile + 1) * 16 + row;
                const int cl2 = (deg > 0) ? ((el2 < deg) ? el2 : deg - 1) : 0;
                const int idx2 = (deg > 0) ? off + cl2 : 0;
                s_n = csr_s[idx2];
                d_n = dist[idx2];
            }

            {
                const int kb0 = hf * 8 + kq * 2;
#pragma unroll
                for (int i = 0; i < 2; ++i) {
                    const int kb = kb0 + i;
                    const int k0 = kb * 8;
                    bf16x8 a  = (i == 0) ? a_c0 : a_c1;
                    bf16x8 bb = *(const bf16x8*)(&bsl[rcv][k0]);
                    float4 w0 = *(const float4*)(w3s + k0);
                    float4 w1 = *(const float4*)(w3s + k0 + 4);
                    bf16x8 af;
                    af[0] = (__bf16)silu_f((float)a[0] + (float)bb[0] + d_c * w0.x);
                    af[1] = (__bf16)silu_f((float)a[1] + (float)bb[1] + d_c * w0.y);
                    af[2] = (__bf16)silu_f((float)a[2] + (float)bb[2] + d_c * w0.z);
                    af[3] = (__bf16)silu_f((float)a[3] + (float)bb[3] + d_c * w0.w);
                    af[4] = (__bf16)silu_f((float)a[4] + (float)bb[4] + d_c * w1.x);
                    af[5] = (__bf16)silu_f((float)a[5] + (float)bb[5] + d_c * w1.y);
                    af[6] = (__bf16)silu_f((float)a[6] + (float)bb[6] + d_c * w1.z);
                    af[7] = (__bf16)silu_f((float)a[7] + (float)bb[7] + d_c * w1.w);
                    *(bf16x8*)(hbuf + row * 136 + kb * 8) = af;
                }
            }

            if (more) {
                const int kb0 = hf * 8 + kq * 2;
                a_c0 = *(const bf16x8*)(AB + (size_t)s_n * 256 + kb0 * 8);
                a_c1 = *(const bf16x8*)(AB + (size_t)s_n * 256 + (kb0 + 1) * 8);
            }
            __syncthreads();

            f32x4 acc[4] = {};
#pragma unroll
            for (int c = 0; c < 4; ++c) {
                const int kb2 = c * 4 + kq;
                bf16x8 af = *(const bf16x8*)(hbuf + row * 136 + kb2 * 8);
#pragma unroll
                for (int t4 = 0; t4 < 4; ++t4) {
                    const int j  = (hf * 4 + t4) * 16 + row;
                    const int jb = j & 7;
                    bf16x8 b = *(const bf16x8*)(wt + (j << 7) + ((kb2 ^ jb) << 3));
                    acc[t4] = MFMA16(af, b, acc[t4], 0, 0, 0);
                }
            }
#pragma unroll
            for (int t4 = 0; t4 < 4; ++t4) {
                const float bb = b2s[(hf * 4 + t4) * 16 + row];
#pragma unroll
                for (int q = 0; q < 4; ++q) {
                    const int er = tile * 16 + kq * 4 + q;
                    if (er < deg) colacc[t4] += silu_f(acc[t4][q] + bb);
                }
            }

            s_c = s_n; d_c = d_n;
        }

#pragma unroll
        for (int t4 = 0; t4 < 4; ++t4) {
            float vv = colacc[t4];
            vv += __shfl_xor(vv, 16, 64);
            vv += __shfl_xor(vv, 32, 64);
            colacc[t4] = vv;
        }
        if (valid && kq == 0) {
#pragma unroll
            for (int t4 = 0; t4 < 4; ++t4)
                aggr[(size_t)myr * 128 + (hf * 4 + t4) * 16 + row] = colacc[t4];
        }
    }
}

// -------- phase 3: u = silu(x@U1a + aggr@U1b + c1), bf16, IN PLACE over aggr
__global__ __launch_bounds__(256) void k_node2(
    const float* __restrict__ x, const float* __restrict__ aggr,
    const float* __restrict__ U1, const float* __restrict__ c1,
    __bf16* __restrict__ u, int N, int ngroups)
{
    __shared__ __bf16 wt[128 * 256];
    for (int idx = threadIdx.x; idx < 128 * 256; idx += 256) {
        int j = idx & 127, k = idx >> 7;
        wt[(j << 8) + ((((k >> 3) ^ (j & 7))) << 3) + (k & 7)] = (__bf16)U1[(k << 7) + j];
    }
    __syncthreads();

    const int lane = threadIdx.x & 63;
    const int row  = lane & 15;
    const int kq   = lane >> 4;

    for (int g = blockIdx.x; g < ngroups; g += gridDim.x) {
        const int row0 = g * 64 + (threadIdx.x >> 6) * 16;
        int m = row0 + row; if (m >= N) m = N - 1;

        bf16x8 afr[8];
#pragma unroll
        for (int c = 0; c < 8; ++c) {
            const int k0 = (c & 3) * 32 + kq * 8;
            const float* src = (c < 4) ? (x + (size_t)m * 128 + k0)
                                       : (aggr + (size_t)m * 128 + k0);
            float4 a0 = *(const float4*)(src);
            float4 a1 = *(const float4*)(src + 4);
            bf16x8 af;
            af[0]=(__bf16)a0.x; af[1]=(__bf16)a0.y; af[2]=(__bf16)a0.z; af[3]=(__bf16)a0.w;
            af[4]=(__bf16)a1.x; af[5]=(__bf16)a1.y; af[6]=(__bf16)a1.z; af[7]=(__bf16)a1.w;
            afr[c] = af;
        }

        f32x4 acc[8] = {};
#pragma unroll
        for (int t = 0; t < 8; ++t) {
            const int j  = t * 16 + row;
            const int jb = j & 7;
            const __bf16* base = wt + (j << 8);
#pragma unroll
            for (int c = 0; c < 8; ++c) {
                const int kb = c * 4 + kq;
                bf16x8 b = *(const bf16x8*)(base + ((kb ^ jb) << 3));
                acc[t] = MFMA16(afr[c], b, acc[t], 0, 0, 0);
            }
        }

#pragma unroll
        for (int t = 0; t < 8; ++t) {
            const int col = t * 16 + row;
            const float cc = c1[col];
#pragma unroll
            for (int q = 0; q < 4; ++q) {
                const int gr = row0 + kq * 4 + q;
                if (gr < N) u[(size_t)gr * 256 + col] = (__bf16)silu_f(acc[t][q] + cc);
            }
        }
    }
}

// ---------------- phase 4: out = u@U2 + c2 (overwrites AB in d_out) ---------
__global__ __launch_bounds__(256) void k_node3(
    const __bf16* __restrict__ u, const float* __restrict__ U2,
    const float* __restrict__ c2, float* __restrict__ out, int N, int ngroups)
{
    __shared__ __bf16 wt[128 * 128];
    for (int idx = threadIdx.x; idx < 128 * 128; idx += 256) {
        int j = idx & 127, k = idx >> 7;
        wt[(j << 7) + ((((k >> 3) ^ (j & 7))) << 3) + (k & 7)] = (__bf16)U2[(k << 7) + j];
    }
    __syncthreads();

    const int lane = threadIdx.x & 63;
    const int row  = lane & 15;
    const int kq   = lane >> 4;

    for (int g = blockIdx.x; g < ngroups; g += gridDim.x) {
        const int row0 = g * 64 + (threadIdx.x >> 6) * 16;
        int m = row0 + row; if (m >= N) m = N - 1;

        bf16x8 afr[4];
#pragma unroll
        for (int c = 0; c < 4; ++c) {
            const int k0 = c * 32 + kq * 8;
            afr[c] = *(const bf16x8*)(u + (size_t)m * 256 + k0);
        }

        f32x4 acc[8] = {};
#pragma unroll
        for (int t = 0; t < 8; ++t) {
            const int j  = t * 16 + row;
            const int jb = j & 7;
            const __bf16* base = wt + (j << 7);
#pragma unroll
            for (int c = 0; c < 4; ++c) {
                const int kb = c * 4 + kq;
                bf16x8 b = *(const bf16x8*)(base + ((kb ^ jb) << 3));
                acc[t] = MFMA16(afr[c], b, acc[t], 0, 0, 0);
            }
        }

#pragma unroll
        for (int t = 0; t < 8; ++t) {
            const int col = t * 16 + row;
            const float cc = c2[col];
#pragma unroll
            for (int q = 0; q < 4; ++q) {
                const int gr = row0 + kq * 4 + q;
                if (gr < N) out[(size_t)gr * 128 + col] = acc[t][q] + cc;
            }
        }
    }
}

extern "C" void kernel_launch(void* const* d_in, const int* in_sizes, int n_in,
                              void* d_out, int out_size, void* d_ws, size_t ws_size,
                              hipStream_t stream) {
    (void)n_in; (void)out_size;
    const float* x   = (const float*)d_in[0];
    const float* pos = (const float*)d_in[1];
    const int*   ei  = (const int*)d_in[2];
    const float* W1  = (const float*)d_in[3];
    const float* b1  = (const float*)d_in[4];
    const float* W2  = (const float*)d_in[5];
    const float* b2  = (const float*)d_in[6];
    const float* U1  = (const float*)d_in[7];
    const float* c1  = (const float*)d_in[8];
    const float* U2  = (const float*)d_in[9];
    const float* c2  = (const float*)d_in[10];

    const int N = in_sizes[0] / 128;
    const int E = in_sizes[2] / 2;

    // ---- workspace layout (16B-aligned slabs) ----
    const size_t aggr_b = (size_t)N * 128 * sizeof(float);
    const size_t Ni_b   = (((size_t)N * 4) + 15) & ~(size_t)15;
    const size_t E_b    = (((size_t)E * 4) + 15) & ~(size_t)15;
    size_t off = 0;
    char* base = (char*)d_ws;
    float* aggr   = (float*)(base + off); off += aggr_b;
    int*   flag   = (int*)  (base + off); off += 16;
    int*   counts = (int*)  (base + off); off += Ni_b;
    int*   offs   = (int*)  (base + off); off += Ni_b;
    int*   cursor = (int*)  (base + off); off += Ni_b;
    int*   parts  = (int*)  (base + off); off += 256 * 4;
    int*   csr_s  = (int*)  (base + off); off += E_b;
    int*   csr_r  = (int*)  (base + off); off += E_b;
    float* dist   = (float*)(base + off); off += E_b;
    const size_t need_csr = off;

    __bf16* u  = (__bf16*)d_ws;        // row stride 256 elem, aliases aggr
    __bf16* AB = (__bf16*)d_out;       // N*256 bf16 == out_nbytes

    const int nblk_scan = (N + 511) / 512;
    const bool csr_ok = (ws_size >= need_csr) && (nblk_scan <= 256);
    if (ws_size < aggr_b + 16 || !csr_ok) return;

    // calibrated selection (r16 ground truth: <=128 regs = 4 waves/SIMD ok)
    hipFuncAttributes fa3{};
    const bool use_p3 =
        (hipFuncGetAttributes(&fa3, (const void*)k_edge_p3) == hipSuccess) &&
        (fa3.numRegs <= 128);

    const int ng_nodes = (N + 63) / 64;
    const int grid_n   = ng_nodes < 512 ? ng_nodes : 512;
    const int grid_E   = (E + 255) / 256;
    const int grid_Nt  = (N + 255) / 256;
    const int nquad    = (N + 3) / 4;
    const int grid_q   = nquad < 2048 ? nquad : 2048;
    const int npair    = (N + 1) / 2;
    const int grid_p   = npair < 2048 ? npair : 2048;

    k_detect<<<1, 256, 0, stream>>>(ei, flag);
    k_node1<<<grid_n, 256, 0, stream>>>(x, W1, b1, AB, N, ng_nodes);

    hipMemsetAsync(counts, 0, (size_t)N * 4, stream);
    k_hist   <<<grid_E, 256, 0, stream>>>(ei, flag, counts, E);
    k_scan1  <<<nblk_scan, 256, 0, stream>>>(counts, offs, parts, N);
    k_scan2  <<<1, 256, 0, stream>>>(parts, nblk_scan);
    k_scan3  <<<grid_Nt, 256, 0, stream>>>(offs, parts, cursor, N);
    k_scatter<<<grid_E, 256, 0, stream>>>(ei, flag, pos, cursor,
                                          csr_s, csr_r, dist, E);

    if (use_p3) {
        k_edge_p3<<<grid_q, 256, 0, stream>>>(AB, csr_s, dist, offs, counts,
                                              W2, b2, W1 + 256 * 128, aggr, N);
    } else {
        k_edge_p2<<<grid_p, 256, 0, stream>>>(AB, csr_s, dist, offs, counts,
                                              W2, b2, W1 + 256 * 128, aggr, N);
    }

    k_node2<<<grid_n, 256, 0, stream>>>(x, aggr, U1, c1, u, N, ng_nodes);
    k_node3<<<grid_n, 256, 0, stream>>>(u, U2, c2, (float*)d_out, N, ng_nodes);
}